// Round 12
// baseline (501.071 us; speedup 1.0000x reference)
//
#include <hip/hip_runtime.h>
#include <math.h>
#include <stdint.h>

#define NN 2048
#define HH 64

typedef _Float16 half8 __attribute__((ext_vector_type(8)));
typedef _Float16 half2_t __attribute__((ext_vector_type(2)));
typedef float f32x4 __attribute__((ext_vector_type(4)));

#define SH (1.0f / 256.0f)
#define INV_SH 256.0f
#define BPAD 132  // f32 row stride; js row stride = 16*132*4 = 8448 B (asm imm)

#if defined(__has_builtin)
#if __has_builtin(__builtin_amdgcn_cvt_pkrtz)
#define PKRTZ(a, b) ((half2_t)__builtin_amdgcn_cvt_pkrtz((a), (b)))
#endif
#endif
#ifndef PKRTZ
#define PKRTZ(a, b) ((half2_t){(_Float16)(a), (_Float16)(b)})
#endif

union H8u { half2_t h2[4]; half8 h8; };

// ---------- layer 0: x0 = relu((adj @ nf) @ W0 + b0), nf is (N,4) ----------
__global__ __launch_bounds__(256) void gcn0_kernel(const float* __restrict__ adj,
                                                   const float* __restrict__ nf,
                                                   const float* __restrict__ W0,
                                                   const float* __restrict__ b0,
                                                   float* __restrict__ xout) {
  int w = threadIdx.x >> 6;
  int l = threadIdx.x & 63;
  int i = blockIdx.x * 4 + w;
  const float* arow = adj + (size_t)i * NN;
  double s0 = 0, s1 = 0, s2 = 0, s3 = 0;
  for (int k = l; k < NN; k += 64) {
    float a = arow[k];
    float4 v = *(const float4*)(nf + (size_t)k * 4);
    s0 += (double)a * (double)v.x;
    s1 += (double)a * (double)v.y;
    s2 += (double)a * (double)v.z;
    s3 += (double)a * (double)v.w;
  }
  #pragma unroll
  for (int m = 32; m >= 1; m >>= 1) {
    s0 += __shfl_xor(s0, m, 64);
    s1 += __shfl_xor(s1, m, 64);
    s2 += __shfl_xor(s2, m, 64);
    s3 += __shfl_xor(s3, m, 64);
  }
  double y = (double)b0[l];
  y += s0 * (double)W0[0 * HH + l];
  y += s1 * (double)W0[1 * HH + l];
  y += s2 * (double)W0[2 * HH + l];
  y += s3 * (double)W0[3 * HH + l];
  float r = (float)y;
  xout[(size_t)i * HH + l] = r > 0.f ? r : 0.f;
}

// ---------- layers 1,2: xout = relu((adj @ xin) @ W + b); layer2 fuses A/B ----------
#define KT 128
__global__ __launch_bounds__(256) void gcnL_kernel(const float* __restrict__ adj,
                                                   const float* __restrict__ xin,
                                                   const float* __restrict__ W,
                                                   const float* __restrict__ b,
                                                   float* __restrict__ xout,
                                                   const float* __restrict__ We1,
                                                   const float* __restrict__ be1,
                                                   float* __restrict__ Aout,
                                                   float* __restrict__ Bout) {
  __shared__ float xs[KT][HH];
  __shared__ float adjs[4][KT];
  __shared__ double sred[4][HH];
  __shared__ float xr2[4][HH];
  int tid = threadIdx.x;
  int w = tid >> 6, l = tid & 63;
  int i0 = blockIdx.x * 4;
  double a0 = 0.0, a1 = 0.0, a2 = 0.0, a3 = 0.0;
  for (int k0 = 0; k0 < NN; k0 += KT) {
    __syncthreads();
    const float4* xsrc = (const float4*)(xin + (size_t)k0 * HH);
    float4* xdst = (float4*)&xs[0][0];
    for (int idx = tid; idx < KT * HH / 4; idx += 256) xdst[idx] = xsrc[idx];
    for (int idx = tid; idx < 4 * KT / 4; idx += 256) {
      int r = idx >> 5, c4 = idx & 31;
      *(float4*)&adjs[r][c4 * 4] =
          *(const float4*)(adj + (size_t)(i0 + r) * NN + k0 + c4 * 4);
    }
    __syncthreads();
    #pragma unroll 8
    for (int kk = 0; kk < KT; kk += 4) {
      float4 av = *(const float4*)&adjs[w][kk];   // wave-uniform b128 broadcast
      a0 += (double)av.x * (double)xs[kk + 0][l];
      a1 += (double)av.y * (double)xs[kk + 1][l];
      a2 += (double)av.z * (double)xs[kk + 2][l];
      a3 += (double)av.w * (double)xs[kk + 3][l];
    }
  }
  sred[w][l] = (a0 + a1) + (a2 + a3);
  __syncthreads();
  double y = (double)b[l];
  #pragma unroll 8
  for (int d = 0; d < HH; ++d) y += sred[w][d] * (double)W[d * HH + l];
  float r = (float)y;
  float rres = r > 0.f ? r : 0.f;
  xout[(size_t)(i0 + w) * HH + l] = rres;
  if (Aout != nullptr) {
    xr2[w][l] = rres;
    __syncthreads();
    #pragma unroll
    for (int t = 0; t < 2; ++t) {
      int idx = tid + t * 256;         // 0..511
      int rr = idx >> 7, c = idx & 127;
      const float* xr = xr2[rr];
      float accA = be1[c], accB = 0.f;
      #pragma unroll 8
      for (int d = 0; d < HH; ++d) {
        float xv = xr[d];
        accA = fmaf(xv, We1[d * 128 + c], accA);
        accB = fmaf(xv, We1[(HH + d) * 128 + c], accB);
      }
      Aout[(size_t)(i0 + rr) * 128 + c] = accA * SH;
      Bout[(size_t)(i0 + rr) * 128 + c] = accB * SH;
    }
  }
}

// ---------- one-shot We2 split: Wh/Wl f16 [c2][k] row-major ----------
__global__ __launch_bounds__(256) void wsplit_kernel(const float* __restrict__ We2,
                                                     _Float16* __restrict__ Whg,
                                                     _Float16* __restrict__ Wlg) {
  int idx = blockIdx.x * 256 + threadIdx.x;   // 0..8191
  int k = idx >> 6, c2 = idx & 63;
  float wv = We2[idx];
  _Float16 hi = (_Float16)wv;
  float lo = wv - (float)hi;
  Whg[c2 * 128 + k] = hi;
  Wlg[c2 * 128 + k] = (_Float16)lo;
}

// ---------- pair MLP via MFMA (split-f16), 16i x 64j tile, 4 waves ----------
// v7: inline-asm prefetch pipeline. All inner-loop LDS reads are asm
// ds_read_b128 into two named sets (E/O) with counted s_waitcnt lgkmcnt(15)
// + sched_barrier(0) (guide T3/T4 + rule #18) so the compiler cannot
// de-pipeline (round-11 failure: VGPR fell to 88, loads sunk to uses).
// Set = 16 reads: B 8 (js*8448 imm, +16) + W 8 (nt*4096 imm, lo +16384).
// A rows preloaded per pass from GLOBAL (vmcnt — separate counter, does not
// drain the lgkm prefetch queue).
struct PfSet { float4 b0[4], b1[4]; half8 wh[4], wl[4]; };

#define ISSUE(S, aB, aW) do {                                                   \
  asm volatile("ds_read_b128 %0, %1 offset:0"     : "=v"((S).b0[0]) : "v"(aB)); \
  asm volatile("ds_read_b128 %0, %1 offset:16"    : "=v"((S).b1[0]) : "v"(aB)); \
  asm volatile("ds_read_b128 %0, %1 offset:8448"  : "=v"((S).b0[1]) : "v"(aB)); \
  asm volatile("ds_read_b128 %0, %1 offset:8464"  : "=v"((S).b1[1]) : "v"(aB)); \
  asm volatile("ds_read_b128 %0, %1 offset:16896" : "=v"((S).b0[2]) : "v"(aB)); \
  asm volatile("ds_read_b128 %0, %1 offset:16912" : "=v"((S).b1[2]) : "v"(aB)); \
  asm volatile("ds_read_b128 %0, %1 offset:25344" : "=v"((S).b0[3]) : "v"(aB)); \
  asm volatile("ds_read_b128 %0, %1 offset:25360" : "=v"((S).b1[3]) : "v"(aB)); \
  asm volatile("ds_read_b128 %0, %1 offset:0"     : "=v"((S).wh[0]) : "v"(aW)); \
  asm volatile("ds_read_b128 %0, %1 offset:4096"  : "=v"((S).wh[1]) : "v"(aW)); \
  asm volatile("ds_read_b128 %0, %1 offset:8192"  : "=v"((S).wh[2]) : "v"(aW)); \
  asm volatile("ds_read_b128 %0, %1 offset:12288" : "=v"((S).wh[3]) : "v"(aW)); \
  asm volatile("ds_read_b128 %0, %1 offset:16384" : "=v"((S).wl[0]) : "v"(aW)); \
  asm volatile("ds_read_b128 %0, %1 offset:20480" : "=v"((S).wl[1]) : "v"(aW)); \
  asm volatile("ds_read_b128 %0, %1 offset:24576" : "=v"((S).wl[2]) : "v"(aW)); \
  asm volatile("ds_read_b128 %0, %1 offset:28672" : "=v"((S).wl[3]) : "v"(aW)); \
} while (0)

#define WAIT15 do { asm volatile("s_waitcnt lgkmcnt(15)" ::: "memory"); \
                    __builtin_amdgcn_sched_barrier(0); } while (0)
#define WAIT0  do { asm volatile("s_waitcnt lgkmcnt(0)"  ::: "memory"); \
                    __builtin_amdgcn_sched_barrier(0); } while (0)

__global__ __launch_bounds__(256, 1) void pair_kernel(const float* __restrict__ A,
                                                      const float* __restrict__ B,
                                                      const _Float16* __restrict__ Whg,
                                                      const _Float16* __restrict__ Wlg,
                                                      const float* __restrict__ be2,
                                                      const float* __restrict__ We3,
                                                      const float* __restrict__ be3,
                                                      float* __restrict__ out) {
  int j0 = blockIdx.x * 64;
  int i0 = blockIdx.y * 16;
  if (i0 >= j0 + 63) return;         // no pair (i<j) in tile
  __shared__ __align__(16) _Float16 Wst8[2048 * 8];  // 32 KB, [Wh|Wl] swizzled
  __shared__ __align__(16) float Bs[64][BPAD];       // 33.8 KB
  __shared__ float be2s[64];
  __shared__ float We3s[64];
  int tid = threadIdx.x;
  int w = tid >> 6, l = tid & 63;
  int r = l & 15, g = l >> 4;

  {
    half8* Wst = (half8*)Wst8;
    #pragma unroll
    for (int t = 0; t < 8; ++t) {
      int idx = tid + t * 256;       // 0..2047
      int arr = idx >> 10;           // 0 = Wh, 1 = Wl
      int c = idx & 1023;
      int row = c >> 4, ch = c & 15;
      const half8* src = arr ? (const half8*)Wlg : (const half8*)Whg;
      Wst[arr * 1024 + row * 16 + (ch ^ (row & 15))] = src[c];
    }
  }
  #pragma unroll
  for (int t = 0; t < 8; ++t) {
    int idx = tid + t * 256;         // 0..2047
    int rr = idx >> 5, c4 = idx & 31;
    *(float4*)&Bs[rr][c4 * 4] = *(const float4*)(B + (size_t)(j0 + rr) * 128 + c4 * 4);
  }
  if (tid < 64) { be2s[tid] = be2[tid]; We3s[tid] = We3[tid]; }
  __syncthreads();

  float be3v = be3[0];
  float w3[4], sb[4];
  #pragma unroll
  for (int nt = 0; nt < 4; ++nt) {
    w3[nt] = We3s[nt * 16 + r];
    sb[nt] = SH * be2s[nt * 16 + r];
  }

  // LDS byte addresses for the asm reads (low 32 bits of flat LDS addr = offset)
  uint32_t addrB = (uint32_t)(uintptr_t)&Bs[r][8 * g];
  uint32_t wbase = (uint32_t)(uintptr_t)&Wst8[0] +
                   (uint32_t)((r * 16 + (g ^ (r & 3))) * 16);
  int rr2 = r >> 2;
  uint32_t addrWk0 = wbase + (uint32_t)(((0 ^ rr2)) << 6);
  uint32_t addrWk1 = wbase + (uint32_t)(((1 ^ rr2)) << 6);
  uint32_t addrWk2 = wbase + (uint32_t)(((2 ^ rr2)) << 6);
  uint32_t addrWk3 = wbase + (uint32_t)(((3 ^ rr2)) << 6);

  #pragma unroll 1
  for (int p = 0; p < 4; ++p) {
    int ir = w * 4 + p;              // wave-uniform
    int i = i0 + ir;
    if (i >= j0 + 63) continue;
    const float* Arow = A + (size_t)i * 128;

    // A preload for all 4 ks (global, vmcnt-tracked)
    float4 aP0[4], aP1[4];
    #pragma unroll
    for (int ks = 0; ks < 4; ++ks) {
      aP0[ks] = *(const float4*)(Arow + ks * 32 + 8 * g);
      aP1[ks] = *(const float4*)(Arow + ks * 32 + 8 * g + 4);
    }

    f32x4 acc[4][4];
    #pragma unroll
    for (int js = 0; js < 4; ++js) {
      #pragma unroll
      for (int nt = 0; nt < 4; ++nt) {
        acc[js][nt][0] = sb[nt]; acc[js][nt][1] = sb[nt];
        acc[js][nt][2] = sb[nt]; acc[js][nt][3] = sb[nt];
      }
    }

#define COMPUTE(S, KS) do {                                                   \
    _Pragma("unroll")                                                         \
    for (int js = 0; js < 4; ++js) {                                          \
      float s0 = fmaxf(aP0[KS].x + (S).b0[js].x, 0.f);                        \
      float s1 = fmaxf(aP0[KS].y + (S).b0[js].y, 0.f);                        \
      float s2 = fmaxf(aP0[KS].z + (S).b0[js].z, 0.f);                        \
      float s3 = fmaxf(aP0[KS].w + (S).b0[js].w, 0.f);                        \
      float s4 = fmaxf(aP1[KS].x + (S).b1[js].x, 0.f);                        \
      float s5 = fmaxf(aP1[KS].y + (S).b1[js].y, 0.f);                        \
      float s6 = fmaxf(aP1[KS].z + (S).b1[js].z, 0.f);                        \
      float s7 = fmaxf(aP1[KS].w + (S).b1[js].w, 0.f);                        \
      H8u hh, hl;                                                             \
      hh.h2[0] = PKRTZ(s0, s1);                                               \
      hh.h2[1] = PKRTZ(s2, s3);                                               \
      hh.h2[2] = PKRTZ(s4, s5);                                               \
      hh.h2[3] = PKRTZ(s6, s7);                                               \
      hl.h2[0] = PKRTZ(s0 - (float)hh.h2[0][0], s1 - (float)hh.h2[0][1]);     \
      hl.h2[1] = PKRTZ(s2 - (float)hh.h2[1][0], s3 - (float)hh.h2[1][1]);     \
      hl.h2[2] = PKRTZ(s4 - (float)hh.h2[2][0], s5 - (float)hh.h2[2][1]);     \
      hl.h2[3] = PKRTZ(s6 - (float)hh.h2[3][0], s7 - (float)hh.h2[3][1]);     \
      _Pragma("unroll")                                                       \
      for (int nt = 0; nt < 4; ++nt) {                                        \
        acc[js][nt] = __builtin_amdgcn_mfma_f32_16x16x32_f16(hh.h8, (S).wh[nt], acc[js][nt], 0, 0, 0); \
        acc[js][nt] = __builtin_amdgcn_mfma_f32_16x16x32_f16(hh.h8, (S).wl[nt], acc[js][nt], 0, 0, 0); \
        acc[js][nt] = __builtin_amdgcn_mfma_f32_16x16x32_f16(hl.h8, (S).wh[nt], acc[js][nt], 0, 0, 0); \
      }                                                                       \
    }                                                                         \
  } while (0)

    PfSet E, O;
    ISSUE(E, addrB, addrWk0);                // ks0
    ISSUE(O, addrB + 128u, addrWk1);         // ks1
    WAIT15; COMPUTE(E, 0);
    ISSUE(E, addrB + 256u, addrWk2);         // ks2
    WAIT15; COMPUTE(O, 1);
    ISSUE(O, addrB + 384u, addrWk3);         // ks3
    WAIT15; COMPUTE(E, 2);
    WAIT0;  COMPUTE(O, 3);
#undef COMPUTE

    // epilogue: h2 = relu(acc)/SH; logit = sum h2*We3 + be3
    #pragma unroll
    for (int js = 0; js < 4; ++js) {
      float p0 = 0.f, p1 = 0.f, p2 = 0.f, p3 = 0.f;
      #pragma unroll
      for (int nt = 0; nt < 4; ++nt) {
        f32x4 v = acc[js][nt];
        p0 += fmaxf(v[0], 0.f) * w3[nt];
        p1 += fmaxf(v[1], 0.f) * w3[nt];
        p2 += fmaxf(v[2], 0.f) * w3[nt];
        p3 += fmaxf(v[3], 0.f) * w3[nt];
      }
      #pragma unroll
      for (int m = 1; m <= 8; m <<= 1) {
        p0 += __shfl_xor(p0, m, 64);
        p1 += __shfl_xor(p1, m, 64);
        p2 += __shfl_xor(p2, m, 64);
        p3 += __shfl_xor(p3, m, 64);
      }
      if (r == 0) {
        int jb2 = j0 + js * 16 + 4 * g;
        int j;
        float logit;
        j = jb2 + 0;
        if (j > i) {
          logit = p0 * INV_SH + be3v;
          out[i * (NN - 1) - (i * (i - 1)) / 2 + (j - i - 1)] =
              1.0f / (1.0f + expf(-logit));
        }
        j = jb2 + 1;
        if (j > i) {
          logit = p1 * INV_SH + be3v;
          out[i * (NN - 1) - (i * (i - 1)) / 2 + (j - i - 1)] =
              1.0f / (1.0f + expf(-logit));
        }
        j = jb2 + 2;
        if (j > i) {
          logit = p2 * INV_SH + be3v;
          out[i * (NN - 1) - (i * (i - 1)) / 2 + (j - i - 1)] =
              1.0f / (1.0f + expf(-logit));
        }
        j = jb2 + 3;
        if (j > i) {
          logit = p3 * INV_SH + be3v;
          out[i * (NN - 1) - (i * (i - 1)) / 2 + (j - i - 1)] =
              1.0f / (1.0f + expf(-logit));
        }
      }
    }
  }
}

extern "C" void kernel_launch(void* const* d_in, const int* in_sizes, int n_in,
                              void* d_out, int out_size, void* d_ws, size_t ws_size,
                              hipStream_t stream) {
  (void)in_sizes; (void)n_in; (void)out_size; (void)ws_size;
  const float* nf  = (const float*)d_in[0];
  const float* adj = (const float*)d_in[1];
  const float* W0  = (const float*)d_in[2];
  const float* b0  = (const float*)d_in[3];
  const float* W1  = (const float*)d_in[4];
  const float* b1  = (const float*)d_in[5];
  const float* W2  = (const float*)d_in[6];
  const float* b2  = (const float*)d_in[7];
  const float* We1 = (const float*)d_in[8];
  const float* be1 = (const float*)d_in[9];
  const float* We2 = (const float*)d_in[10];
  const float* be2 = (const float*)d_in[11];
  const float* We3 = (const float*)d_in[12];
  const float* be3 = (const float*)d_in[13];
  float* out = (float*)d_out;

  // Workspace layout (max 3584 KB):
  //  [0,512K):    x0, later overwritten by x2 (x0 dead after layer 1)
  //  [512K,1024K): x1
  //  [1024K,1040K): Whg ; [1040K,1056K): Wlg
  //  [1536K,2560K): Ab ; [2560K,3584K): Bb
  char* ws = (char*)d_ws;
  float* x0 = (float*)(ws);
  float* x1 = (float*)(ws + (512 << 10));
  float* x2 = (float*)(ws);                        // reuse x0 slot
  _Float16* Whg = (_Float16*)(ws + (1024 << 10));  // 16 KB
  _Float16* Wlg = (_Float16*)(ws + (1040 << 10));  // 16 KB
  float* Ab = (float*)(ws + (1536 << 10));         // 1 MB (pre-scaled)
  float* Bb = (float*)(ws + (2560 << 10));         // 1 MB (pre-scaled)

  wsplit_kernel<<<32, 256, 0, stream>>>(We2, Whg, Wlg);
  gcn0_kernel<<<NN / 4, 256, 0, stream>>>(adj, nf, W0, b0, x0);
  gcnL_kernel<<<NN / 4, 256, 0, stream>>>(adj, x0, W1, b1, x1,
                                          nullptr, nullptr, nullptr, nullptr);
  gcnL_kernel<<<NN / 4, 256, 0, stream>>>(adj, x1, W2, b2, x2,
                                          We1, be1, Ab, Bb);
  pair_kernel<<<dim3(NN / 64, NN / 16), 256, 0, stream>>>(Ab, Bb, Whg, Wlg,
                                                          be2, We3, be3, out);
}

// Round 13
// 433.083 us; speedup vs baseline: 1.1570x; 1.1570x over previous
//
#include <hip/hip_runtime.h>
#include <math.h>

#define NN 2048
#define HH 64
#define NPAIR 2096128

typedef _Float16 half8 __attribute__((ext_vector_type(8)));
typedef _Float16 half2_t __attribute__((ext_vector_type(2)));
typedef float f32x4 __attribute__((ext_vector_type(4)));

#define SH (1.0f / 256.0f)
#define INV_SH 256.0f
#define BPAD 132  // f32 row stride

#if defined(__has_builtin)
#if __has_builtin(__builtin_amdgcn_cvt_pkrtz)
#define PKRTZ(a, b) ((half2_t)__builtin_amdgcn_cvt_pkrtz((a), (b)))
#endif
#endif
#ifndef PKRTZ
#define PKRTZ(a, b) ((half2_t){(_Float16)(a), (_Float16)(b)})
#endif

union H8u { half2_t h2[4]; half8 h8; };

// ---------- layer 0: x0 = relu((adj @ nf) @ W0 + b0), nf is (N,4) ----------
__global__ __launch_bounds__(256) void gcn0_kernel(const float* __restrict__ adj,
                                                   const float* __restrict__ nf,
                                                   const float* __restrict__ W0,
                                                   const float* __restrict__ b0,
                                                   float* __restrict__ xout) {
  int w = threadIdx.x >> 6;
  int l = threadIdx.x & 63;
  int i = blockIdx.x * 4 + w;
  const float* arow = adj + (size_t)i * NN;
  double s0 = 0, s1 = 0, s2 = 0, s3 = 0;
  for (int k = l; k < NN; k += 64) {
    float a = arow[k];
    float4 v = *(const float4*)(nf + (size_t)k * 4);
    s0 += (double)a * (double)v.x;
    s1 += (double)a * (double)v.y;
    s2 += (double)a * (double)v.z;
    s3 += (double)a * (double)v.w;
  }
  #pragma unroll
  for (int m = 32; m >= 1; m >>= 1) {
    s0 += __shfl_xor(s0, m, 64);
    s1 += __shfl_xor(s1, m, 64);
    s2 += __shfl_xor(s2, m, 64);
    s3 += __shfl_xor(s3, m, 64);
  }
  double y = (double)b0[l];
  y += s0 * (double)W0[0 * HH + l];
  y += s1 * (double)W0[1 * HH + l];
  y += s2 * (double)W0[2 * HH + l];
  y += s3 * (double)W0[3 * HH + l];
  float r = (float)y;
  xout[(size_t)i * HH + l] = r > 0.f ? r : 0.f;
}

// ---------- layers 1,2: xout = relu((adj @ xin) @ W + b); layer2 fuses A/B ----------
#define KT 128
__global__ __launch_bounds__(256) void gcnL_kernel(const float* __restrict__ adj,
                                                   const float* __restrict__ xin,
                                                   const float* __restrict__ W,
                                                   const float* __restrict__ b,
                                                   float* __restrict__ xout,
                                                   const float* __restrict__ We1,
                                                   const float* __restrict__ be1,
                                                   float* __restrict__ Aout,
                                                   float* __restrict__ Bout) {
  __shared__ float xs[KT][HH];
  __shared__ float adjs[4][KT];
  __shared__ double sred[4][HH];
  __shared__ float xr2[4][HH];
  int tid = threadIdx.x;
  int w = tid >> 6, l = tid & 63;
  int i0 = blockIdx.x * 4;
  double a0 = 0.0, a1 = 0.0, a2 = 0.0, a3 = 0.0;
  for (int k0 = 0; k0 < NN; k0 += KT) {
    __syncthreads();
    const float4* xsrc = (const float4*)(xin + (size_t)k0 * HH);
    float4* xdst = (float4*)&xs[0][0];
    for (int idx = tid; idx < KT * HH / 4; idx += 256) xdst[idx] = xsrc[idx];
    for (int idx = tid; idx < 4 * KT / 4; idx += 256) {
      int r = idx >> 5, c4 = idx & 31;
      *(float4*)&adjs[r][c4 * 4] =
          *(const float4*)(adj + (size_t)(i0 + r) * NN + k0 + c4 * 4);
    }
    __syncthreads();
    #pragma unroll 8
    for (int kk = 0; kk < KT; kk += 4) {
      float4 av = *(const float4*)&adjs[w][kk];   // wave-uniform b128 broadcast
      a0 += (double)av.x * (double)xs[kk + 0][l];
      a1 += (double)av.y * (double)xs[kk + 1][l];
      a2 += (double)av.z * (double)xs[kk + 2][l];
      a3 += (double)av.w * (double)xs[kk + 3][l];
    }
  }
  sred[w][l] = (a0 + a1) + (a2 + a3);
  __syncthreads();
  double y = (double)b[l];
  #pragma unroll 8
  for (int d = 0; d < HH; ++d) y += sred[w][d] * (double)W[d * HH + l];
  float r = (float)y;
  float rres = r > 0.f ? r : 0.f;
  xout[(size_t)(i0 + w) * HH + l] = rres;
  if (Aout != nullptr) {
    xr2[w][l] = rres;
    __syncthreads();
    #pragma unroll
    for (int t = 0; t < 2; ++t) {
      int idx = tid + t * 256;         // 0..511
      int rr = idx >> 7, c = idx & 127;
      const float* xr = xr2[rr];
      float accA = be1[c], accB = 0.f;
      #pragma unroll 8
      for (int d = 0; d < HH; ++d) {
        float xv = xr[d];
        accA = fmaf(xv, We1[d * 128 + c], accA);
        accB = fmaf(xv, We1[(HH + d) * 128 + c], accB);
      }
      Aout[(size_t)(i0 + rr) * 128 + c] = accA * SH;
      Bout[(size_t)(i0 + rr) * 128 + c] = accB * SH;
    }
  }
}

// ---------- one-shot We2 split: Wh/Wl f16 [c2][k] row-major ----------
__global__ __launch_bounds__(256) void wsplit_kernel(const float* __restrict__ We2,
                                                     _Float16* __restrict__ Whg,
                                                     _Float16* __restrict__ Wlg) {
  int idx = blockIdx.x * 256 + threadIdx.x;   // 0..8191
  int k = idx >> 6, c2 = idx & 63;
  float wv = We2[idx];
  _Float16 hi = (_Float16)wv;
  float lo = wv - (float)hi;
  Whg[c2 * 128 + k] = hi;
  Wlg[c2 * 128 + k] = (_Float16)lo;
}

// ---------- pair MLP via MFMA (split-f16), 16i x 64j x 32c2-half tiles ----------
// v8: OCCUPANCY-FIRST. blockIdx.z splits c2 into 2 halves -> acc is only
// 4js x 2nt x f32x4 = 32 regs/thread; total ~110 VGPR -> 4 waves/SIMD by regs,
// LDS = Bs 33.8K + W-half 16K ~ 51K -> 3 blocks/CU = 12 waves/CU (3x rounds
// 4-12, which ran at 1 wave/SIMD due to 128-reg accumulators - the plateau).
// Each z-block atomicAdds its half-logit into out (exactly 2 commuting f32
// adds per output -> deterministic); sig_kernel then applies sigmoid(x+be3).
__global__ __launch_bounds__(256, 4) void pair_kernel(const float* __restrict__ A,
                                                      const float* __restrict__ B,
                                                      const _Float16* __restrict__ Whg,
                                                      const _Float16* __restrict__ Wlg,
                                                      const float* __restrict__ be2,
                                                      const float* __restrict__ We3,
                                                      float* __restrict__ outAcc) {
  int j0 = blockIdx.x * 64;
  int i0 = blockIdx.y * 16;
  int z  = blockIdx.z;               // c2 half: c2 = z*32 + nt*16 + r
  if (i0 >= j0 + 63) return;         // no pair (i<j) in tile
  __shared__ __align__(16) _Float16 Wst8[1024 * 8];  // 16 KB: [hi 512 | lo 512] chunks
  __shared__ __align__(16) float Bs[64][BPAD];       // 33.8 KB
  __shared__ float be2s[32];
  __shared__ float We3s[32];
  int tid = threadIdx.x;
  int w = tid >> 6, l = tid & 63;
  int r = l & 15, g = l >> 4;

  {
    half8* Wst = (half8*)Wst8;
    const half8* srcH = (const half8*)(Whg + (size_t)z * 32 * 128);
    const half8* srcL = (const half8*)(Wlg + (size_t)z * 32 * 128);
    #pragma unroll
    for (int t = 0; t < 4; ++t) {
      int idx = tid + t * 256;       // 0..1023
      int arr = idx >> 9;            // 0 = hi, 1 = lo
      int c = idx & 511;             // 32 rows x 16 chunks
      int row = c >> 4, ch = c & 15;
      const half8* src = arr ? srcL : srcH;
      Wst[arr * 512 + row * 16 + (ch ^ (row & 15))] = src[c];
    }
  }
  #pragma unroll
  for (int t = 0; t < 8; ++t) {
    int idx = tid + t * 256;         // 0..2047
    int rr = idx >> 5, c4 = idx & 31;
    *(float4*)&Bs[rr][c4 * 4] = *(const float4*)(B + (size_t)(j0 + rr) * 128 + c4 * 4);
  }
  if (tid < 32) { be2s[tid] = be2[z * 32 + tid]; We3s[tid] = We3[z * 32 + tid]; }
  __syncthreads();

  const half8* Wst = (const half8*)Wst8;
  float w3[2], sb[2];
  #pragma unroll
  for (int nt = 0; nt < 2; ++nt) {
    w3[nt] = We3s[nt * 16 + r];
    sb[nt] = SH * be2s[nt * 16 + r];
  }

  #pragma unroll 1
  for (int p = 0; p < 4; ++p) {
    int ir = w * 4 + p;              // wave-uniform
    int i = i0 + ir;
    if (i >= j0 + 63) continue;
    const float* Arow = A + (size_t)i * 128;
    f32x4 acc[4][2];
    #pragma unroll
    for (int js = 0; js < 4; ++js) {
      #pragma unroll
      for (int nt = 0; nt < 2; ++nt) {
        acc[js][nt][0] = sb[nt]; acc[js][nt][1] = sb[nt];
        acc[js][nt][2] = sb[nt]; acc[js][nt][3] = sb[nt];
      }
    }
    #pragma unroll
    for (int ks = 0; ks < 4; ++ks) {
      int kb = ks * 32 + 8 * g;
      half8 wh[2], wl[2];
      #pragma unroll
      for (int nt = 0; nt < 2; ++nt) {
        int a = (nt * 16 + r) * 16 + ((ks * 4 + g) ^ r);
        wh[nt] = Wst[a];
        wl[nt] = Wst[512 + a];
      }
      float4 a0 = *(const float4*)(Arow + kb);      // L1-resident, wave-uniform row
      float4 a1 = *(const float4*)(Arow + kb + 4);
      #pragma unroll
      for (int js = 0; js < 4; ++js) {
        float4 b0 = *(const float4*)&Bs[js * 16 + r][kb];
        float4 b1 = *(const float4*)&Bs[js * 16 + r][kb + 4];
        float s0 = fmaxf(a0.x + b0.x, 0.f);
        float s1 = fmaxf(a0.y + b0.y, 0.f);
        float s2 = fmaxf(a0.z + b0.z, 0.f);
        float s3 = fmaxf(a0.w + b0.w, 0.f);
        float s4 = fmaxf(a1.x + b1.x, 0.f);
        float s5 = fmaxf(a1.y + b1.y, 0.f);
        float s6 = fmaxf(a1.z + b1.z, 0.f);
        float s7 = fmaxf(a1.w + b1.w, 0.f);
        H8u hh, hl;
        hh.h2[0] = PKRTZ(s0, s1);
        hh.h2[1] = PKRTZ(s2, s3);
        hh.h2[2] = PKRTZ(s4, s5);
        hh.h2[3] = PKRTZ(s6, s7);
        hl.h2[0] = PKRTZ(s0 - (float)hh.h2[0][0], s1 - (float)hh.h2[0][1]);
        hl.h2[1] = PKRTZ(s2 - (float)hh.h2[1][0], s3 - (float)hh.h2[1][1]);
        hl.h2[2] = PKRTZ(s4 - (float)hh.h2[2][0], s5 - (float)hh.h2[2][1]);
        hl.h2[3] = PKRTZ(s6 - (float)hh.h2[3][0], s7 - (float)hh.h2[3][1]);
        #pragma unroll
        for (int nt = 0; nt < 2; ++nt) {
          acc[js][nt] = __builtin_amdgcn_mfma_f32_16x16x32_f16(hh.h8, wh[nt], acc[js][nt], 0, 0, 0);
          acc[js][nt] = __builtin_amdgcn_mfma_f32_16x16x32_f16(hh.h8, wl[nt], acc[js][nt], 0, 0, 0);
          acc[js][nt] = __builtin_amdgcn_mfma_f32_16x16x32_f16(hl.h8, wh[nt], acc[js][nt], 0, 0, 0);
        }
      }
    }
    // epilogue: half-logit partials; reduce over the 16 r-lanes; atomicAdd
    #pragma unroll
    for (int js = 0; js < 4; ++js) {
      float p0 = 0.f, p1 = 0.f, p2 = 0.f, p3 = 0.f;
      #pragma unroll
      for (int nt = 0; nt < 2; ++nt) {
        f32x4 v = acc[js][nt];
        p0 += fmaxf(v[0], 0.f) * w3[nt];
        p1 += fmaxf(v[1], 0.f) * w3[nt];
        p2 += fmaxf(v[2], 0.f) * w3[nt];
        p3 += fmaxf(v[3], 0.f) * w3[nt];
      }
      #pragma unroll
      for (int m = 1; m <= 8; m <<= 1) {
        p0 += __shfl_xor(p0, m, 64);
        p1 += __shfl_xor(p1, m, 64);
        p2 += __shfl_xor(p2, m, 64);
        p3 += __shfl_xor(p3, m, 64);
      }
      if (r == 0) {
        int jb2 = j0 + js * 16 + 4 * g;
        int j;
        j = jb2 + 0;
        if (j > i) atomicAdd(&outAcc[i * (NN - 1) - (i * (i - 1)) / 2 + (j - i - 1)], p0 * INV_SH);
        j = jb2 + 1;
        if (j > i) atomicAdd(&outAcc[i * (NN - 1) - (i * (i - 1)) / 2 + (j - i - 1)], p1 * INV_SH);
        j = jb2 + 2;
        if (j > i) atomicAdd(&outAcc[i * (NN - 1) - (i * (i - 1)) / 2 + (j - i - 1)], p2 * INV_SH);
        j = jb2 + 3;
        if (j > i) atomicAdd(&outAcc[i * (NN - 1) - (i * (i - 1)) / 2 + (j - i - 1)], p3 * INV_SH);
      }
    }
  }
}

// ---------- final: out = sigmoid(out + be3), in place ----------
__global__ __launch_bounds__(256) void sig_kernel(float* __restrict__ out,
                                                  const float* __restrict__ be3,
                                                  int n) {
  int idx = blockIdx.x * 256 + threadIdx.x;
  float b = be3[0];
  if (idx < n) {
    float v = out[idx] + b;
    out[idx] = 1.0f / (1.0f + expf(-v));
  }
}

extern "C" void kernel_launch(void* const* d_in, const int* in_sizes, int n_in,
                              void* d_out, int out_size, void* d_ws, size_t ws_size,
                              hipStream_t stream) {
  (void)in_sizes; (void)n_in; (void)ws_size;
  const float* nf  = (const float*)d_in[0];
  const float* adj = (const float*)d_in[1];
  const float* W0  = (const float*)d_in[2];
  const float* b0  = (const float*)d_in[3];
  const float* W1  = (const float*)d_in[4];
  const float* b1  = (const float*)d_in[5];
  const float* W2  = (const float*)d_in[6];
  const float* b2  = (const float*)d_in[7];
  const float* We1 = (const float*)d_in[8];
  const float* be1 = (const float*)d_in[9];
  const float* We2 = (const float*)d_in[10];
  const float* be2 = (const float*)d_in[11];
  const float* We3 = (const float*)d_in[12];
  const float* be3 = (const float*)d_in[13];
  float* out = (float*)d_out;

  // Workspace layout (max 3584 KB):
  //  [0,512K):    x0, later overwritten by x2 (x0 dead after layer 1)
  //  [512K,1024K): x1
  //  [1024K,1040K): Whg ; [1040K,1056K): Wlg
  //  [1536K,2560K): Ab ; [2560K,3584K): Bb
  char* ws = (char*)d_ws;
  float* x0 = (float*)(ws);
  float* x1 = (float*)(ws + (512 << 10));
  float* x2 = (float*)(ws);                        // reuse x0 slot
  _Float16* Whg = (_Float16*)(ws + (1024 << 10));  // 16 KB
  _Float16* Wlg = (_Float16*)(ws + (1040 << 10));  // 16 KB
  float* Ab = (float*)(ws + (1536 << 10));         // 1 MB (pre-scaled)
  float* Bb = (float*)(ws + (2560 << 10));         // 1 MB (pre-scaled)

  // out doubles as the logit accumulator: zero it, atomically accumulate the
  // two c2-half partials, then sigmoid in place.
  hipMemsetAsync(out, 0, (size_t)out_size * sizeof(float), stream);

  wsplit_kernel<<<32, 256, 0, stream>>>(We2, Whg, Wlg);
  gcn0_kernel<<<NN / 4, 256, 0, stream>>>(adj, nf, W0, b0, x0);
  gcnL_kernel<<<NN / 4, 256, 0, stream>>>(adj, x0, W1, b1, x1,
                                          nullptr, nullptr, nullptr, nullptr);
  gcnL_kernel<<<NN / 4, 256, 0, stream>>>(adj, x1, W2, b2, x2,
                                          We1, be1, Ab, Bb);
  pair_kernel<<<dim3(NN / 64, NN / 16, 2), 256, 0, stream>>>(Ab, Bb, Whg, Wlg,
                                                             be2, We3, out);
  sig_kernel<<<(NPAIR + 255) / 256, 256, 0, stream>>>(out, be3, NPAIR);
}

// Round 14
// 313.913 us; speedup vs baseline: 1.5962x; 1.3796x over previous
//
#include <hip/hip_runtime.h>
#include <math.h>

#define NN 2048
#define HH 64

typedef _Float16 half8 __attribute__((ext_vector_type(8)));
typedef _Float16 half2_t __attribute__((ext_vector_type(2)));
typedef float f32x4 __attribute__((ext_vector_type(4)));

#define SH (1.0f / 256.0f)
#define INV_SH 256.0f
#define BPAD 132  // f32 row stride: 2-way bank phases (free)

#if defined(__has_builtin)
#if __has_builtin(__builtin_amdgcn_cvt_pkrtz)
#define PKRTZ(a, b) ((half2_t)__builtin_amdgcn_cvt_pkrtz((a), (b)))
#endif
#endif
#ifndef PKRTZ
#define PKRTZ(a, b) ((half2_t){(_Float16)(a), (_Float16)(b)})
#endif

union H8u { half2_t h2[4]; half8 h8; };

// ---------- layer 0: x0 = relu((adj @ nf) @ W0 + b0), nf is (N,4) ----------
__global__ __launch_bounds__(256) void gcn0_kernel(const float* __restrict__ adj,
                                                   const float* __restrict__ nf,
                                                   const float* __restrict__ W0,
                                                   const float* __restrict__ b0,
                                                   float* __restrict__ xout) {
  int w = threadIdx.x >> 6;
  int l = threadIdx.x & 63;
  int i = blockIdx.x * 4 + w;
  const float* arow = adj + (size_t)i * NN;
  double s0 = 0, s1 = 0, s2 = 0, s3 = 0;
  for (int k = l; k < NN; k += 64) {
    float a = arow[k];
    float4 v = *(const float4*)(nf + (size_t)k * 4);
    s0 += (double)a * (double)v.x;
    s1 += (double)a * (double)v.y;
    s2 += (double)a * (double)v.z;
    s3 += (double)a * (double)v.w;
  }
  #pragma unroll
  for (int m = 32; m >= 1; m >>= 1) {
    s0 += __shfl_xor(s0, m, 64);
    s1 += __shfl_xor(s1, m, 64);
    s2 += __shfl_xor(s2, m, 64);
    s3 += __shfl_xor(s3, m, 64);
  }
  double y = (double)b0[l];
  y += s0 * (double)W0[0 * HH + l];
  y += s1 * (double)W0[1 * HH + l];
  y += s2 * (double)W0[2 * HH + l];
  y += s3 * (double)W0[3 * HH + l];
  float r = (float)y;
  xout[(size_t)i * HH + l] = r > 0.f ? r : 0.f;
}

// ---------- layers 1,2: xout = relu((adj @ xin) @ W + b); layer2 fuses A/B ----------
#define KT 128
__global__ __launch_bounds__(256) void gcnL_kernel(const float* __restrict__ adj,
                                                   const float* __restrict__ xin,
                                                   const float* __restrict__ W,
                                                   const float* __restrict__ b,
                                                   float* __restrict__ xout,
                                                   const float* __restrict__ We1,
                                                   const float* __restrict__ be1,
                                                   float* __restrict__ Aout,
                                                   float* __restrict__ Bout) {
  __shared__ float xs[KT][HH];
  __shared__ float adjs[4][KT];
  __shared__ double sred[4][HH];
  __shared__ float xr2[4][HH];
  int tid = threadIdx.x;
  int w = tid >> 6, l = tid & 63;
  int i0 = blockIdx.x * 4;
  double a0 = 0.0, a1 = 0.0, a2 = 0.0, a3 = 0.0;
  for (int k0 = 0; k0 < NN; k0 += KT) {
    __syncthreads();
    const float4* xsrc = (const float4*)(xin + (size_t)k0 * HH);
    float4* xdst = (float4*)&xs[0][0];
    for (int idx = tid; idx < KT * HH / 4; idx += 256) xdst[idx] = xsrc[idx];
    for (int idx = tid; idx < 4 * KT / 4; idx += 256) {
      int r = idx >> 5, c4 = idx & 31;
      *(float4*)&adjs[r][c4 * 4] =
          *(const float4*)(adj + (size_t)(i0 + r) * NN + k0 + c4 * 4);
    }
    __syncthreads();
    #pragma unroll 8
    for (int kk = 0; kk < KT; kk += 4) {
      a0 += (double)adjs[w][kk + 0] * (double)xs[kk + 0][l];
      a1 += (double)adjs[w][kk + 1] * (double)xs[kk + 1][l];
      a2 += (double)adjs[w][kk + 2] * (double)xs[kk + 2][l];
      a3 += (double)adjs[w][kk + 3] * (double)xs[kk + 3][l];
    }
  }
  sred[w][l] = (a0 + a1) + (a2 + a3);
  __syncthreads();
  double y = (double)b[l];
  #pragma unroll 8
  for (int d = 0; d < HH; ++d) y += sred[w][d] * (double)W[d * HH + l];
  float r = (float)y;
  float rres = r > 0.f ? r : 0.f;
  xout[(size_t)(i0 + w) * HH + l] = rres;
  if (Aout != nullptr) {
    xr2[w][l] = rres;
    __syncthreads();
    #pragma unroll
    for (int t = 0; t < 2; ++t) {
      int idx = tid + t * 256;         // 0..511
      int rr = idx >> 7, c = idx & 127;
      const float* xr = xr2[rr];
      float accA = be1[c], accB = 0.f;
      #pragma unroll 8
      for (int d = 0; d < HH; ++d) {
        float xv = xr[d];
        accA = fmaf(xv, We1[d * 128 + c], accA);
        accB = fmaf(xv, We1[(HH + d) * 128 + c], accB);
      }
      Aout[(size_t)(i0 + rr) * 128 + c] = accA * SH;
      Bout[(size_t)(i0 + rr) * 128 + c] = accB * SH;
    }
  }
}

// ---------- one-shot We2 split: Wh/Wl f16 [c2][k] row-major ----------
__global__ __launch_bounds__(256) void wsplit_kernel(const float* __restrict__ We2,
                                                     _Float16* __restrict__ Whg,
                                                     _Float16* __restrict__ Wlg) {
  int idx = blockIdx.x * 256 + threadIdx.x;   // 0..8191
  int k = idx >> 6, c2 = idx & 63;
  float wv = We2[idx];
  _Float16 hi = (_Float16)wv;
  float lo = wv - (float)hi;
  Whg[c2 * 128 + k] = hi;
  Wlg[c2 * 128 + k] = (_Float16)lo;
}

// ---------- pair MLP via MFMA (split-f16), 16i x 32j tile, 4 waves ----------
// v9: SMALL ACCUMULATOR WITHOUT WORK DUPLICATION. js=2 (32-j tile) shrinks acc
// to 2x4xf32x4 = 32 regs (vs 64/128 in rounds 4-12 -> 1 wave/SIMD plateau),
// h-formation count unchanged, W loads amortized over js, no atomics.
// Regs ~120 -> launch_bounds(256,4); LDS = W 32K + Bs 16.9K ~ 49.5K -> 3
// blocks/CU -> 12 waves/CU target (3x round-10's 1.3/SIMD).
__global__ __launch_bounds__(256, 4) void pair_kernel(const float* __restrict__ A,
                                                      const float* __restrict__ B,
                                                      const _Float16* __restrict__ Whg,
                                                      const _Float16* __restrict__ Wlg,
                                                      const float* __restrict__ be2,
                                                      const float* __restrict__ We3,
                                                      const float* __restrict__ be3,
                                                      float* __restrict__ out) {
  int j0 = blockIdx.x * 32;
  int i0 = blockIdx.y * 16;
  if (i0 >= j0 + 31) return;         // no pair (i<j) in tile
  __shared__ __align__(16) _Float16 Wst8[2048 * 8];  // 32 KB, [Wh|Wl] swizzled
  __shared__ __align__(16) float Bs[32][BPAD];       // 16.9 KB
  __shared__ float be2s[64];
  __shared__ float We3s[64];
  int tid = threadIdx.x;
  int w = tid >> 6, l = tid & 63;
  int r = l & 15, g = l >> 4;

  {
    half8* Wst = (half8*)Wst8;
    #pragma unroll
    for (int t = 0; t < 8; ++t) {
      int idx = tid + t * 256;       // 0..2047
      int arr = idx >> 10;           // 0 = Wh, 1 = Wl
      int c = idx & 1023;
      int row = c >> 4, ch = c & 15;
      const half8* src = arr ? (const half8*)Wlg : (const half8*)Whg;
      Wst[arr * 1024 + row * 16 + (ch ^ (row & 15))] = src[c];
    }
  }
  #pragma unroll
  for (int t = 0; t < 4; ++t) {
    int idx = tid + t * 256;         // 0..1023
    int rr = idx >> 5, c4 = idx & 31;
    *(float4*)&Bs[rr][c4 * 4] = *(const float4*)(B + (size_t)(j0 + rr) * 128 + c4 * 4);
  }
  if (tid < 64) { be2s[tid] = be2[tid]; We3s[tid] = We3[tid]; }
  __syncthreads();

  const half8* Wst = (const half8*)Wst8;
  float be3v = be3[0];
  float w3[4], sb[4];
  #pragma unroll
  for (int nt = 0; nt < 4; ++nt) {
    w3[nt] = We3s[nt * 16 + r];
    sb[nt] = SH * be2s[nt * 16 + r];
  }

  #pragma unroll 1
  for (int p = 0; p < 4; ++p) {
    int ir = w * 4 + p;              // wave-uniform
    int i = i0 + ir;
    if (i >= j0 + 31) continue;
    const float* Arow = A + (size_t)i * 128;
    f32x4 acc[2][4];
    #pragma unroll
    for (int js = 0; js < 2; ++js) {
      #pragma unroll
      for (int nt = 0; nt < 4; ++nt) {
        acc[js][nt][0] = sb[nt]; acc[js][nt][1] = sb[nt];
        acc[js][nt][2] = sb[nt]; acc[js][nt][3] = sb[nt];
      }
    }
    #pragma unroll
    for (int ks = 0; ks < 4; ++ks) {
      int kb = ks * 32 + 8 * g;
      half8 wh[4], wl[4];
      #pragma unroll
      for (int nt = 0; nt < 4; ++nt) {
        int a = (nt * 16 + r) * 16 + ((ks * 4 + g) ^ r);
        wh[nt] = Wst[a];
        wl[nt] = Wst[1024 + a];
      }
      float4 a0 = *(const float4*)(Arow + kb);      // L1/L2-resident, uniform row
      float4 a1 = *(const float4*)(Arow + kb + 4);
      #pragma unroll
      for (int js = 0; js < 2; ++js) {
        float4 b0 = *(const float4*)&Bs[js * 16 + r][kb];
        float4 b1 = *(const float4*)&Bs[js * 16 + r][kb + 4];
        float s0 = fmaxf(a0.x + b0.x, 0.f);
        float s1 = fmaxf(a0.y + b0.y, 0.f);
        float s2 = fmaxf(a0.z + b0.z, 0.f);
        float s3 = fmaxf(a0.w + b0.w, 0.f);
        float s4 = fmaxf(a1.x + b1.x, 0.f);
        float s5 = fmaxf(a1.y + b1.y, 0.f);
        float s6 = fmaxf(a1.z + b1.z, 0.f);
        float s7 = fmaxf(a1.w + b1.w, 0.f);
        H8u hh, hl;
        hh.h2[0] = PKRTZ(s0, s1);
        hh.h2[1] = PKRTZ(s2, s3);
        hh.h2[2] = PKRTZ(s4, s5);
        hh.h2[3] = PKRTZ(s6, s7);
        hl.h2[0] = PKRTZ(s0 - (float)hh.h2[0][0], s1 - (float)hh.h2[0][1]);
        hl.h2[1] = PKRTZ(s2 - (float)hh.h2[1][0], s3 - (float)hh.h2[1][1]);
        hl.h2[2] = PKRTZ(s4 - (float)hh.h2[2][0], s5 - (float)hh.h2[2][1]);
        hl.h2[3] = PKRTZ(s6 - (float)hh.h2[3][0], s7 - (float)hh.h2[3][1]);
        #pragma unroll
        for (int nt = 0; nt < 4; ++nt) {
          acc[js][nt] = __builtin_amdgcn_mfma_f32_16x16x32_f16(hh.h8, wh[nt], acc[js][nt], 0, 0, 0);
          acc[js][nt] = __builtin_amdgcn_mfma_f32_16x16x32_f16(hh.h8, wl[nt], acc[js][nt], 0, 0, 0);
          acc[js][nt] = __builtin_amdgcn_mfma_f32_16x16x32_f16(hl.h8, wh[nt], acc[js][nt], 0, 0, 0);
        }
      }
    }
    // epilogue: h2 = relu(acc)/SH; logit = sum h2*We3 + be3; direct store
    #pragma unroll
    for (int js = 0; js < 2; ++js) {
      float p0 = 0.f, p1 = 0.f, p2 = 0.f, p3 = 0.f;
      #pragma unroll
      for (int nt = 0; nt < 4; ++nt) {
        f32x4 v = acc[js][nt];
        p0 += fmaxf(v[0], 0.f) * w3[nt];
        p1 += fmaxf(v[1], 0.f) * w3[nt];
        p2 += fmaxf(v[2], 0.f) * w3[nt];
        p3 += fmaxf(v[3], 0.f) * w3[nt];
      }
      #pragma unroll
      for (int m = 1; m <= 8; m <<= 1) {
        p0 += __shfl_xor(p0, m, 64);
        p1 += __shfl_xor(p1, m, 64);
        p2 += __shfl_xor(p2, m, 64);
        p3 += __shfl_xor(p3, m, 64);
      }
      if (r == 0) {
        int jb2 = j0 + js * 16 + 4 * g;
        int j;
        float logit;
        j = jb2 + 0;
        if (j > i) {
          logit = p0 * INV_SH + be3v;
          out[i * (NN - 1) - (i * (i - 1)) / 2 + (j - i - 1)] =
              1.0f / (1.0f + expf(-logit));
        }
        j = jb2 + 1;
        if (j > i) {
          logit = p1 * INV_SH + be3v;
          out[i * (NN - 1) - (i * (i - 1)) / 2 + (j - i - 1)] =
              1.0f / (1.0f + expf(-logit));
        }
        j = jb2 + 2;
        if (j > i) {
          logit = p2 * INV_SH + be3v;
          out[i * (NN - 1) - (i * (i - 1)) / 2 + (j - i - 1)] =
              1.0f / (1.0f + expf(-logit));
        }
        j = jb2 + 3;
        if (j > i) {
          logit = p3 * INV_SH + be3v;
          out[i * (NN - 1) - (i * (i - 1)) / 2 + (j - i - 1)] =
              1.0f / (1.0f + expf(-logit));
        }
      }
    }
  }
}

extern "C" void kernel_launch(void* const* d_in, const int* in_sizes, int n_in,
                              void* d_out, int out_size, void* d_ws, size_t ws_size,
                              hipStream_t stream) {
  (void)in_sizes; (void)n_in; (void)out_size; (void)ws_size;
  const float* nf  = (const float*)d_in[0];
  const float* adj = (const float*)d_in[1];
  const float* W0  = (const float*)d_in[2];
  const float* b0  = (const float*)d_in[3];
  const float* W1  = (const float*)d_in[4];
  const float* b1  = (const float*)d_in[5];
  const float* W2  = (const float*)d_in[6];
  const float* b2  = (const float*)d_in[7];
  const float* We1 = (const float*)d_in[8];
  const float* be1 = (const float*)d_in[9];
  const float* We2 = (const float*)d_in[10];
  const float* be2 = (const float*)d_in[11];
  const float* We3 = (const float*)d_in[12];
  const float* be3 = (const float*)d_in[13];
  float* out = (float*)d_out;

  // Workspace layout (max 3584 KB):
  //  [0,512K):    x0, later overwritten by x2 (x0 dead after layer 1)
  //  [512K,1024K): x1
  //  [1024K,1040K): Whg ; [1040K,1056K): Wlg
  //  [1536K,2560K): Ab ; [2560K,3584K): Bb
  char* ws = (char*)d_ws;
  float* x0 = (float*)(ws);
  float* x1 = (float*)(ws + (512 << 10));
  float* x2 = (float*)(ws);                        // reuse x0 slot
  _Float16* Whg = (_Float16*)(ws + (1024 << 10));  // 16 KB
  _Float16* Wlg = (_Float16*)(ws + (1040 << 10));  // 16 KB
  float* Ab = (float*)(ws + (1536 << 10));         // 1 MB (pre-scaled)
  float* Bb = (float*)(ws + (2560 << 10));         // 1 MB (pre-scaled)

  wsplit_kernel<<<32, 256, 0, stream>>>(We2, Whg, Wlg);
  gcn0_kernel<<<NN / 4, 256, 0, stream>>>(adj, nf, W0, b0, x0);
  gcnL_kernel<<<NN / 4, 256, 0, stream>>>(adj, x0, W1, b1, x1,
                                          nullptr, nullptr, nullptr, nullptr);
  gcnL_kernel<<<NN / 4, 256, 0, stream>>>(adj, x1, W2, b2, x2,
                                          We1, be1, Ab, Bb);
  pair_kernel<<<dim3(NN / 32, NN / 16), 256, 0, stream>>>(Ab, Bb, Whg, Wlg,
                                                          be2, We3, be3, out);
}

// Round 15
// 304.848 us; speedup vs baseline: 1.6437x; 1.0297x over previous
//
#include <hip/hip_runtime.h>
#include <math.h>

#define NN 2048
#define HH 64

typedef _Float16 half8 __attribute__((ext_vector_type(8)));
typedef _Float16 half2_t __attribute__((ext_vector_type(2)));
typedef float f32x4 __attribute__((ext_vector_type(4)));

#define SH (1.0f / 256.0f)
#define INV_SH 256.0f
#define BPAD 132  // f32 row stride: 2-way bank phases (free)

#if defined(__has_builtin)
#if __has_builtin(__builtin_amdgcn_cvt_pkrtz)
#define PKRTZ(a, b) ((half2_t)__builtin_amdgcn_cvt_pkrtz((a), (b)))
#endif
#endif
#ifndef PKRTZ
#define PKRTZ(a, b) ((half2_t){(_Float16)(a), (_Float16)(b)})
#endif

union H8u { half2_t h2[4]; half8 h8; };

// ---------- layer 0: x0 = relu((adj @ nf) @ W0 + b0), nf is (N,4) ----------
__global__ __launch_bounds__(256) void gcn0_kernel(const float* __restrict__ adj,
                                                   const float* __restrict__ nf,
                                                   const float* __restrict__ W0,
                                                   const float* __restrict__ b0,
                                                   float* __restrict__ xout) {
  int w = threadIdx.x >> 6;
  int l = threadIdx.x & 63;
  int i = blockIdx.x * 4 + w;
  const float* arow = adj + (size_t)i * NN;
  double s0 = 0, s1 = 0, s2 = 0, s3 = 0;
  for (int k = l; k < NN; k += 64) {
    float a = arow[k];
    float4 v = *(const float4*)(nf + (size_t)k * 4);
    s0 += (double)a * (double)v.x;
    s1 += (double)a * (double)v.y;
    s2 += (double)a * (double)v.z;
    s3 += (double)a * (double)v.w;
  }
  #pragma unroll
  for (int m = 32; m >= 1; m >>= 1) {
    s0 += __shfl_xor(s0, m, 64);
    s1 += __shfl_xor(s1, m, 64);
    s2 += __shfl_xor(s2, m, 64);
    s3 += __shfl_xor(s3, m, 64);
  }
  double y = (double)b0[l];
  y += s0 * (double)W0[0 * HH + l];
  y += s1 * (double)W0[1 * HH + l];
  y += s2 * (double)W0[2 * HH + l];
  y += s3 * (double)W0[3 * HH + l];
  float r = (float)y;
  xout[(size_t)i * HH + l] = r > 0.f ? r : 0.f;
}

// ---------- layers 1,2: xout = relu((adj @ xin) @ W + b); layer2 fuses A/B ----------
#define KT 128
__global__ __launch_bounds__(256) void gcnL_kernel(const float* __restrict__ adj,
                                                   const float* __restrict__ xin,
                                                   const float* __restrict__ W,
                                                   const float* __restrict__ b,
                                                   float* __restrict__ xout,
                                                   const float* __restrict__ We1,
                                                   const float* __restrict__ be1,
                                                   float* __restrict__ Aout,
                                                   float* __restrict__ Bout) {
  __shared__ float xs[KT][HH];
  __shared__ float adjs[4][KT];
  __shared__ double sred[4][HH];
  __shared__ float xr2[4][HH];
  int tid = threadIdx.x;
  int w = tid >> 6, l = tid & 63;
  int i0 = blockIdx.x * 4;
  double a0 = 0.0, a1 = 0.0, a2 = 0.0, a3 = 0.0;
  for (int k0 = 0; k0 < NN; k0 += KT) {
    __syncthreads();
    const float4* xsrc = (const float4*)(xin + (size_t)k0 * HH);
    float4* xdst = (float4*)&xs[0][0];
    for (int idx = tid; idx < KT * HH / 4; idx += 256) xdst[idx] = xsrc[idx];
    for (int idx = tid; idx < 4 * KT / 4; idx += 256) {
      int r = idx >> 5, c4 = idx & 31;
      *(float4*)&adjs[r][c4 * 4] =
          *(const float4*)(adj + (size_t)(i0 + r) * NN + k0 + c4 * 4);
    }
    __syncthreads();
    #pragma unroll 8
    for (int kk = 0; kk < KT; kk += 4) {
      a0 += (double)adjs[w][kk + 0] * (double)xs[kk + 0][l];
      a1 += (double)adjs[w][kk + 1] * (double)xs[kk + 1][l];
      a2 += (double)adjs[w][kk + 2] * (double)xs[kk + 2][l];
      a3 += (double)adjs[w][kk + 3] * (double)xs[kk + 3][l];
    }
  }
  sred[w][l] = (a0 + a1) + (a2 + a3);
  __syncthreads();
  double y = (double)b[l];
  #pragma unroll 8
  for (int d = 0; d < HH; ++d) y += sred[w][d] * (double)W[d * HH + l];
  float r = (float)y;
  float rres = r > 0.f ? r : 0.f;
  xout[(size_t)(i0 + w) * HH + l] = rres;
  if (Aout != nullptr) {
    xr2[w][l] = rres;
    __syncthreads();
    #pragma unroll
    for (int t = 0; t < 2; ++t) {
      int idx = tid + t * 256;         // 0..511
      int rr = idx >> 7, c = idx & 127;
      const float* xr = xr2[rr];
      float accA = be1[c], accB = 0.f;
      #pragma unroll 8
      for (int d = 0; d < HH; ++d) {
        float xv = xr[d];
        accA = fmaf(xv, We1[d * 128 + c], accA);
        accB = fmaf(xv, We1[(HH + d) * 128 + c], accB);
      }
      Aout[(size_t)(i0 + rr) * 128 + c] = accA * SH;
      Bout[(size_t)(i0 + rr) * 128 + c] = accB * SH;
    }
  }
}

// ---------- one-shot We2 split: Wh/Wl f16 [c2][k] row-major ----------
__global__ __launch_bounds__(256) void wsplit_kernel(const float* __restrict__ We2,
                                                     _Float16* __restrict__ Whg,
                                                     _Float16* __restrict__ Wlg) {
  int idx = blockIdx.x * 256 + threadIdx.x;   // 0..8191
  int k = idx >> 6, c2 = idx & 63;
  float wv = We2[idx];
  _Float16 hi = (_Float16)wv;
  float lo = wv - (float)hi;
  Whg[c2 * 128 + k] = hi;
  Wlg[c2 * 128 + k] = (_Float16)lo;
}

// ---------- pair MLP via MFMA (split-f16), 32i x 32j tile, 8 waves ----------
// v10: v9 structure (js=2, acc=32 regs, VGPR~68) with 512-thread blocks:
// the 32 KB W-tile is per-block overhead, so doubling waves/block halves its
// per-wave cost. LDS unchanged (49.4K) -> 3 blocks/CU now carry 24 waves/CU
// (6/SIMD) vs round-14's 12. Pure occupancy A/B; inner loop byte-identical.
__global__ __launch_bounds__(512, 4) void pair_kernel(const float* __restrict__ A,
                                                      const float* __restrict__ B,
                                                      const _Float16* __restrict__ Whg,
                                                      const _Float16* __restrict__ Wlg,
                                                      const float* __restrict__ be2,
                                                      const float* __restrict__ We3,
                                                      const float* __restrict__ be3,
                                                      float* __restrict__ out) {
  int j0 = blockIdx.x * 32;
  int i0 = blockIdx.y * 32;
  if (i0 >= j0 + 31) return;         // no pair (i<j) in tile
  __shared__ __align__(16) _Float16 Wst8[2048 * 8];  // 32 KB, [Wh|Wl] swizzled
  __shared__ __align__(16) float Bs[32][BPAD];       // 16.9 KB
  __shared__ float be2s[64];
  __shared__ float We3s[64];
  int tid = threadIdx.x;
  int w = tid >> 6, l = tid & 63;   // 8 waves
  int r = l & 15, g = l >> 4;

  {
    half8* Wst = (half8*)Wst8;
    #pragma unroll
    for (int t = 0; t < 4; ++t) {
      int idx = tid + t * 512;       // 0..2047
      int arr = idx >> 10;           // 0 = Wh, 1 = Wl
      int c = idx & 1023;
      int row = c >> 4, ch = c & 15;
      const half8* src = arr ? (const half8*)Wlg : (const half8*)Whg;
      Wst[arr * 1024 + row * 16 + (ch ^ (row & 15))] = src[c];
    }
  }
  #pragma unroll
  for (int t = 0; t < 2; ++t) {
    int idx = tid + t * 512;         // 0..1023
    int rr = idx >> 5, c4 = idx & 31;
    *(float4*)&Bs[rr][c4 * 4] = *(const float4*)(B + (size_t)(j0 + rr) * 128 + c4 * 4);
  }
  if (tid < 64) { be2s[tid] = be2[tid]; We3s[tid] = We3[tid]; }
  __syncthreads();

  const half8* Wst = (const half8*)Wst8;
  float be3v = be3[0];
  float w3[4], sb[4];
  #pragma unroll
  for (int nt = 0; nt < 4; ++nt) {
    w3[nt] = We3s[nt * 16 + r];
    sb[nt] = SH * be2s[nt * 16 + r];
  }

  #pragma unroll 1
  for (int p = 0; p < 4; ++p) {
    int ir = w * 4 + p;              // wave-uniform, 0..31
    int i = i0 + ir;
    if (i >= j0 + 31) continue;
    const float* Arow = A + (size_t)i * 128;
    f32x4 acc[2][4];
    #pragma unroll
    for (int js = 0; js < 2; ++js) {
      #pragma unroll
      for (int nt = 0; nt < 4; ++nt) {
        acc[js][nt][0] = sb[nt]; acc[js][nt][1] = sb[nt];
        acc[js][nt][2] = sb[nt]; acc[js][nt][3] = sb[nt];
      }
    }
    #pragma unroll
    for (int ks = 0; ks < 4; ++ks) {
      int kb = ks * 32 + 8 * g;
      half8 wh[4], wl[4];
      #pragma unroll
      for (int nt = 0; nt < 4; ++nt) {
        int a = (nt * 16 + r) * 16 + ((ks * 4 + g) ^ r);
        wh[nt] = Wst[a];
        wl[nt] = Wst[1024 + a];
      }
      float4 a0 = *(const float4*)(Arow + kb);      // L1/L2-resident, uniform row
      float4 a1 = *(const float4*)(Arow + kb + 4);
      #pragma unroll
      for (int js = 0; js < 2; ++js) {
        float4 b0 = *(const float4*)&Bs[js * 16 + r][kb];
        float4 b1 = *(const float4*)&Bs[js * 16 + r][kb + 4];
        float s0 = fmaxf(a0.x + b0.x, 0.f);
        float s1 = fmaxf(a0.y + b0.y, 0.f);
        float s2 = fmaxf(a0.z + b0.z, 0.f);
        float s3 = fmaxf(a0.w + b0.w, 0.f);
        float s4 = fmaxf(a1.x + b1.x, 0.f);
        float s5 = fmaxf(a1.y + b1.y, 0.f);
        float s6 = fmaxf(a1.z + b1.z, 0.f);
        float s7 = fmaxf(a1.w + b1.w, 0.f);
        H8u hh, hl;
        hh.h2[0] = PKRTZ(s0, s1);
        hh.h2[1] = PKRTZ(s2, s3);
        hh.h2[2] = PKRTZ(s4, s5);
        hh.h2[3] = PKRTZ(s6, s7);
        hl.h2[0] = PKRTZ(s0 - (float)hh.h2[0][0], s1 - (float)hh.h2[0][1]);
        hl.h2[1] = PKRTZ(s2 - (float)hh.h2[1][0], s3 - (float)hh.h2[1][1]);
        hl.h2[2] = PKRTZ(s4 - (float)hh.h2[2][0], s5 - (float)hh.h2[2][1]);
        hl.h2[3] = PKRTZ(s6 - (float)hh.h2[3][0], s7 - (float)hh.h2[3][1]);
        #pragma unroll
        for (int nt = 0; nt < 4; ++nt) {
          acc[js][nt] = __builtin_amdgcn_mfma_f32_16x16x32_f16(hh.h8, wh[nt], acc[js][nt], 0, 0, 0);
          acc[js][nt] = __builtin_amdgcn_mfma_f32_16x16x32_f16(hh.h8, wl[nt], acc[js][nt], 0, 0, 0);
          acc[js][nt] = __builtin_amdgcn_mfma_f32_16x16x32_f16(hl.h8, wh[nt], acc[js][nt], 0, 0, 0);
        }
      }
    }
    // epilogue: h2 = relu(acc)/SH; logit = sum h2*We3 + be3; direct store
    #pragma unroll
    for (int js = 0; js < 2; ++js) {
      float p0 = 0.f, p1 = 0.f, p2 = 0.f, p3 = 0.f;
      #pragma unroll
      for (int nt = 0; nt < 4; ++nt) {
        f32x4 v = acc[js][nt];
        p0 += fmaxf(v[0], 0.f) * w3[nt];
        p1 += fmaxf(v[1], 0.f) * w3[nt];
        p2 += fmaxf(v[2], 0.f) * w3[nt];
        p3 += fmaxf(v[3], 0.f) * w3[nt];
      }
      #pragma unroll
      for (int m = 1; m <= 8; m <<= 1) {
        p0 += __shfl_xor(p0, m, 64);
        p1 += __shfl_xor(p1, m, 64);
        p2 += __shfl_xor(p2, m, 64);
        p3 += __shfl_xor(p3, m, 64);
      }
      if (r == 0) {
        int jb2 = j0 + js * 16 + 4 * g;
        int j;
        float logit;
        j = jb2 + 0;
        if (j > i) {
          logit = p0 * INV_SH + be3v;
          out[i * (NN - 1) - (i * (i - 1)) / 2 + (j - i - 1)] =
              1.0f / (1.0f + expf(-logit));
        }
        j = jb2 + 1;
        if (j > i) {
          logit = p1 * INV_SH + be3v;
          out[i * (NN - 1) - (i * (i - 1)) / 2 + (j - i - 1)] =
              1.0f / (1.0f + expf(-logit));
        }
        j = jb2 + 2;
        if (j > i) {
          logit = p2 * INV_SH + be3v;
          out[i * (NN - 1) - (i * (i - 1)) / 2 + (j - i - 1)] =
              1.0f / (1.0f + expf(-logit));
        }
        j = jb2 + 3;
        if (j > i) {
          logit = p3 * INV_SH + be3v;
          out[i * (NN - 1) - (i * (i - 1)) / 2 + (j - i - 1)] =
              1.0f / (1.0f + expf(-logit));
        }
      }
    }
  }
}

extern "C" void kernel_launch(void* const* d_in, const int* in_sizes, int n_in,
                              void* d_out, int out_size, void* d_ws, size_t ws_size,
                              hipStream_t stream) {
  (void)in_sizes; (void)n_in; (void)out_size; (void)ws_size;
  const float* nf  = (const float*)d_in[0];
  const float* adj = (const float*)d_in[1];
  const float* W0  = (const float*)d_in[2];
  const float* b0  = (const float*)d_in[3];
  const float* W1  = (const float*)d_in[4];
  const float* b1  = (const float*)d_in[5];
  const float* W2  = (const float*)d_in[6];
  const float* b2  = (const float*)d_in[7];
  const float* We1 = (const float*)d_in[8];
  const float* be1 = (const float*)d_in[9];
  const float* We2 = (const float*)d_in[10];
  const float* be2 = (const float*)d_in[11];
  const float* We3 = (const float*)d_in[12];
  const float* be3 = (const float*)d_in[13];
  float* out = (float*)d_out;

  // Workspace layout (max 3584 KB):
  //  [0,512K):    x0, later overwritten by x2 (x0 dead after layer 1)
  //  [512K,1024K): x1
  //  [1024K,1040K): Whg ; [1040K,1056K): Wlg
  //  [1536K,2560K): Ab ; [2560K,3584K): Bb
  char* ws = (char*)d_ws;
  float* x0 = (float*)(ws);
  float* x1 = (float*)(ws + (512 << 10));
  float* x2 = (float*)(ws);                        // reuse x0 slot
  _Float16* Whg = (_Float16*)(ws + (1024 << 10));  // 16 KB
  _Float16* Wlg = (_Float16*)(ws + (1040 << 10));  // 16 KB
  float* Ab = (float*)(ws + (1536 << 10));         // 1 MB (pre-scaled)
  float* Bb = (float*)(ws + (2560 << 10));         // 1 MB (pre-scaled)

  wsplit_kernel<<<32, 256, 0, stream>>>(We2, Whg, Wlg);
  gcn0_kernel<<<NN / 4, 256, 0, stream>>>(adj, nf, W0, b0, x0);
  gcnL_kernel<<<NN / 4, 256, 0, stream>>>(adj, x0, W1, b1, x1,
                                          nullptr, nullptr, nullptr, nullptr);
  gcnL_kernel<<<NN / 4, 256, 0, stream>>>(adj, x1, W2, b2, x2,
                                          We1, be1, Ab, Bb);
  pair_kernel<<<dim3(NN / 32, NN / 32), 512, 0, stream>>>(Ab, Bb, Whg, Wlg,
                                                          be2, We3, be3, out);
}

// Round 16
// 257.784 us; speedup vs baseline: 1.9438x; 1.1826x over previous
//
#include <hip/hip_runtime.h>
#include <math.h>

#define NN 2048
#define HH 64

typedef _Float16 half8 __attribute__((ext_vector_type(8)));
typedef _Float16 half2_t __attribute__((ext_vector_type(2)));
typedef float f32x4 __attribute__((ext_vector_type(4)));

#define SH (1.0f / 256.0f)
#define INV_SH 256.0f
#define BPAD 132  // f32 row stride: 2-way bank phases (free)

#if defined(__has_builtin)
#if __has_builtin(__builtin_amdgcn_cvt_pkrtz)
#define PKRTZ(a, b) ((half2_t)__builtin_amdgcn_cvt_pkrtz((a), (b)))
#endif
#endif
#ifndef PKRTZ
#define PKRTZ(a, b) ((half2_t){(_Float16)(a), (_Float16)(b)})
#endif

union H8u { half2_t h2[4]; half8 h8; };

// ---------- layer 0: x0 = relu((adj @ nf) @ W0 + b0), nf is (N,4) ----------
__global__ __launch_bounds__(256) void gcn0_kernel(const float* __restrict__ adj,
                                                   const float* __restrict__ nf,
                                                   const float* __restrict__ W0,
                                                   const float* __restrict__ b0,
                                                   float* __restrict__ xout) {
  int w = threadIdx.x >> 6;
  int l = threadIdx.x & 63;
  int i = blockIdx.x * 4 + w;
  const float* arow = adj + (size_t)i * NN;
  double s0 = 0, s1 = 0, s2 = 0, s3 = 0;
  for (int k = l; k < NN; k += 64) {
    float a = arow[k];
    float4 v = *(const float4*)(nf + (size_t)k * 4);
    s0 += (double)a * (double)v.x;
    s1 += (double)a * (double)v.y;
    s2 += (double)a * (double)v.z;
    s3 += (double)a * (double)v.w;
  }
  #pragma unroll
  for (int m = 32; m >= 1; m >>= 1) {
    s0 += __shfl_xor(s0, m, 64);
    s1 += __shfl_xor(s1, m, 64);
    s2 += __shfl_xor(s2, m, 64);
    s3 += __shfl_xor(s3, m, 64);
  }
  double y = (double)b0[l];
  y += s0 * (double)W0[0 * HH + l];
  y += s1 * (double)W0[1 * HH + l];
  y += s2 * (double)W0[2 * HH + l];
  y += s3 * (double)W0[3 * HH + l];
  float r = (float)y;
  xout[(size_t)i * HH + l] = r > 0.f ? r : 0.f;
}

// ---------- layers 1,2: xout = relu((adj @ xin) @ W + b); layer2 fuses A/B ----------
// v2: (a) f32 accumulation for the 2048-term sums (error ~1e-6 rel, budget
// 4e-5 — W-dot epilogue stays f64); (b) K-SPLIT ACROSS WAVES: wave w handles
// kk in [32w,32w+32) for ALL 4 rows -> per tile per wave 32 b32 + 32
// b128-broadcast LDS insts (was 128 b32 + 32: 4 waves redundantly re-read
// the x-tile). Cross-wave reduce via 4 KB LDS.
#define KT 128
__global__ __launch_bounds__(256) void gcnL_kernel(const float* __restrict__ adj,
                                                   const float* __restrict__ xin,
                                                   const float* __restrict__ W,
                                                   const float* __restrict__ b,
                                                   float* __restrict__ xout,
                                                   const float* __restrict__ We1,
                                                   const float* __restrict__ be1,
                                                   float* __restrict__ Aout,
                                                   float* __restrict__ Bout) {
  __shared__ float xs[KT][HH];        // 32 KB [kk][l]
  __shared__ float adjs[4][KT];       // 2 KB  [row][kk]
  __shared__ float sredp[4][4][HH];   // 4 KB  [wave][row][l] K-slice partials
  __shared__ float sredt[4][HH];      // 1 KB  full row sums
  __shared__ float xr2[4][HH];
  int tid = threadIdx.x;
  int w = tid >> 6, l = tid & 63;
  int i0 = blockIdx.x * 4;
  float acc0 = 0.f, acc1 = 0.f, acc2 = 0.f, acc3 = 0.f;  // 4 rows, K-slice [32w,32w+32)
  for (int k0 = 0; k0 < NN; k0 += KT) {
    __syncthreads();
    const float4* xsrc = (const float4*)(xin + (size_t)k0 * HH);
    float4* xdst = (float4*)&xs[0][0];
    for (int idx = tid; idx < KT * HH / 4; idx += 256) xdst[idx] = xsrc[idx];
    for (int idx = tid; idx < 4 * KT / 4; idx += 256) {
      int r = idx >> 5, c4 = idx & 31;
      *(float4*)&adjs[r][c4 * 4] =
          *(const float4*)(adj + (size_t)(i0 + r) * NN + k0 + c4 * 4);
    }
    __syncthreads();
    int kbase = w * 32;
    #pragma unroll
    for (int kq = 0; kq < 8; ++kq) {
      int kk = kbase + kq * 4;
      float4 a0 = *(const float4*)&adjs[0][kk];  // wave-uniform broadcast
      float4 a1 = *(const float4*)&adjs[1][kk];
      float4 a2 = *(const float4*)&adjs[2][kk];
      float4 a3 = *(const float4*)&adjs[3][kk];
      float xv0 = xs[kk + 0][l];
      float xv1 = xs[kk + 1][l];
      float xv2 = xs[kk + 2][l];
      float xv3 = xs[kk + 3][l];
      acc0 = fmaf(a0.w, xv3, fmaf(a0.z, xv2, fmaf(a0.y, xv1, fmaf(a0.x, xv0, acc0))));
      acc1 = fmaf(a1.w, xv3, fmaf(a1.z, xv2, fmaf(a1.y, xv1, fmaf(a1.x, xv0, acc1))));
      acc2 = fmaf(a2.w, xv3, fmaf(a2.z, xv2, fmaf(a2.y, xv1, fmaf(a2.x, xv0, acc2))));
      acc3 = fmaf(a3.w, xv3, fmaf(a3.z, xv2, fmaf(a3.y, xv1, fmaf(a3.x, xv0, acc3))));
    }
  }
  sredp[w][0][l] = acc0;
  sredp[w][1][l] = acc1;
  sredp[w][2][l] = acc2;
  sredp[w][3][l] = acc3;
  __syncthreads();
  // thread (w,l): full sum for row w, column l
  sredt[w][l] = (sredp[0][w][l] + sredp[1][w][l]) + (sredp[2][w][l] + sredp[3][w][l]);
  __syncthreads();
  double y = (double)b[l];
  #pragma unroll 8
  for (int d = 0; d < HH; ++d) y += (double)sredt[w][d] * (double)W[d * HH + l];
  float r = (float)y;
  float rres = r > 0.f ? r : 0.f;
  xout[(size_t)(i0 + w) * HH + l] = rres;
  if (Aout != nullptr) {
    xr2[w][l] = rres;
    __syncthreads();
    #pragma unroll
    for (int t = 0; t < 2; ++t) {
      int idx = tid + t * 256;         // 0..511
      int rr = idx >> 7, c = idx & 127;
      const float* xr = xr2[rr];
      float accA = be1[c], accB = 0.f;
      #pragma unroll 8
      for (int d = 0; d < HH; ++d) {
        float xv = xr[d];
        accA = fmaf(xv, We1[d * 128 + c], accA);
        accB = fmaf(xv, We1[(HH + d) * 128 + c], accB);
      }
      Aout[(size_t)(i0 + rr) * 128 + c] = accA * SH;
      Bout[(size_t)(i0 + rr) * 128 + c] = accB * SH;
    }
  }
}

// ---------- one-shot We2 split: Wh/Wl f16 [c2][k] row-major ----------
__global__ __launch_bounds__(256) void wsplit_kernel(const float* __restrict__ We2,
                                                     _Float16* __restrict__ Whg,
                                                     _Float16* __restrict__ Wlg) {
  int idx = blockIdx.x * 256 + threadIdx.x;   // 0..8191
  int k = idx >> 6, c2 = idx & 63;
  float wv = We2[idx];
  _Float16 hi = (_Float16)wv;
  float lo = wv - (float)hi;
  Whg[c2 * 128 + k] = hi;
  Wlg[c2 * 128 + k] = (_Float16)lo;
}

// ---------- pair MLP via MFMA (split-f16), 32i x 32j tile, 8 waves ----------
// v10 (round 15, unchanged): js=2, acc=32 regs, VGPR 64; 512-thread blocks
// amortize the 32 KB W-tile over 8 waves. 170 us, occ 25%, VALU 57 / MFMA 25.
__global__ __launch_bounds__(512, 4) void pair_kernel(const float* __restrict__ A,
                                                      const float* __restrict__ B,
                                                      const _Float16* __restrict__ Whg,
                                                      const _Float16* __restrict__ Wlg,
                                                      const float* __restrict__ be2,
                                                      const float* __restrict__ We3,
                                                      const float* __restrict__ be3,
                                                      float* __restrict__ out) {
  int j0 = blockIdx.x * 32;
  int i0 = blockIdx.y * 32;
  if (i0 >= j0 + 31) return;         // no pair (i<j) in tile
  __shared__ __align__(16) _Float16 Wst8[2048 * 8];  // 32 KB, [Wh|Wl] swizzled
  __shared__ __align__(16) float Bs[32][BPAD];       // 16.9 KB
  __shared__ float be2s[64];
  __shared__ float We3s[64];
  int tid = threadIdx.x;
  int w = tid >> 6, l = tid & 63;   // 8 waves
  int r = l & 15, g = l >> 4;

  {
    half8* Wst = (half8*)Wst8;
    #pragma unroll
    for (int t = 0; t < 4; ++t) {
      int idx = tid + t * 512;       // 0..2047
      int arr = idx >> 10;           // 0 = Wh, 1 = Wl
      int c = idx & 1023;
      int row = c >> 4, ch = c & 15;
      const half8* src = arr ? (const half8*)Wlg : (const half8*)Whg;
      Wst[arr * 1024 + row * 16 + (ch ^ (row & 15))] = src[c];
    }
  }
  #pragma unroll
  for (int t = 0; t < 2; ++t) {
    int idx = tid + t * 512;         // 0..1023
    int rr = idx >> 5, c4 = idx & 31;
    *(float4*)&Bs[rr][c4 * 4] = *(const float4*)(B + (size_t)(j0 + rr) * 128 + c4 * 4);
  }
  if (tid < 64) { be2s[tid] = be2[tid]; We3s[tid] = We3[tid]; }
  __syncthreads();

  const half8* Wst = (const half8*)Wst8;
  float be3v = be3[0];
  float w3[4], sb[4];
  #pragma unroll
  for (int nt = 0; nt < 4; ++nt) {
    w3[nt] = We3s[nt * 16 + r];
    sb[nt] = SH * be2s[nt * 16 + r];
  }

  #pragma unroll 1
  for (int p = 0; p < 4; ++p) {
    int ir = w * 4 + p;              // wave-uniform, 0..31
    int i = i0 + ir;
    if (i >= j0 + 31) continue;
    const float* Arow = A + (size_t)i * 128;
    f32x4 acc[2][4];
    #pragma unroll
    for (int js = 0; js < 2; ++js) {
      #pragma unroll
      for (int nt = 0; nt < 4; ++nt) {
        acc[js][nt][0] = sb[nt]; acc[js][nt][1] = sb[nt];
        acc[js][nt][2] = sb[nt]; acc[js][nt][3] = sb[nt];
      }
    }
    #pragma unroll
    for (int ks = 0; ks < 4; ++ks) {
      int kb = ks * 32 + 8 * g;
      half8 wh[4], wl[4];
      #pragma unroll
      for (int nt = 0; nt < 4; ++nt) {
        int a = (nt * 16 + r) * 16 + ((ks * 4 + g) ^ r);
        wh[nt] = Wst[a];
        wl[nt] = Wst[1024 + a];
      }
      float4 a0 = *(const float4*)(Arow + kb);      // L1/L2-resident, uniform row
      float4 a1 = *(const float4*)(Arow + kb + 4);
      #pragma unroll
      for (int js = 0; js < 2; ++js) {
        float4 b0 = *(const float4*)&Bs[js * 16 + r][kb];
        float4 b1 = *(const float4*)&Bs[js * 16 + r][kb + 4];
        float s0 = fmaxf(a0.x + b0.x, 0.f);
        float s1 = fmaxf(a0.y + b0.y, 0.f);
        float s2 = fmaxf(a0.z + b0.z, 0.f);
        float s3 = fmaxf(a0.w + b0.w, 0.f);
        float s4 = fmaxf(a1.x + b1.x, 0.f);
        float s5 = fmaxf(a1.y + b1.y, 0.f);
        float s6 = fmaxf(a1.z + b1.z, 0.f);
        float s7 = fmaxf(a1.w + b1.w, 0.f);
        H8u hh, hl;
        hh.h2[0] = PKRTZ(s0, s1);
        hh.h2[1] = PKRTZ(s2, s3);
        hh.h2[2] = PKRTZ(s4, s5);
        hh.h2[3] = PKRTZ(s6, s7);
        hl.h2[0] = PKRTZ(s0 - (float)hh.h2[0][0], s1 - (float)hh.h2[0][1]);
        hl.h2[1] = PKRTZ(s2 - (float)hh.h2[1][0], s3 - (float)hh.h2[1][1]);
        hl.h2[2] = PKRTZ(s4 - (float)hh.h2[2][0], s5 - (float)hh.h2[2][1]);
        hl.h2[3] = PKRTZ(s6 - (float)hh.h2[3][0], s7 - (float)hh.h2[3][1]);
        #pragma unroll
        for (int nt = 0; nt < 4; ++nt) {
          acc[js][nt] = __builtin_amdgcn_mfma_f32_16x16x32_f16(hh.h8, wh[nt], acc[js][nt], 0, 0, 0);
          acc[js][nt] = __builtin_amdgcn_mfma_f32_16x16x32_f16(hh.h8, wl[nt], acc[js][nt], 0, 0, 0);
          acc[js][nt] = __builtin_amdgcn_mfma_f32_16x16x32_f16(hl.h8, wh[nt], acc[js][nt], 0, 0, 0);
        }
      }
    }
    // epilogue: h2 = relu(acc)/SH; logit = sum h2*We3 + be3; direct store
    #pragma unroll
    for (int js = 0; js < 2; ++js) {
      float p0 = 0.f, p1 = 0.f, p2 = 0.f, p3 = 0.f;
      #pragma unroll
      for (int nt = 0; nt < 4; ++nt) {
        f32x4 v = acc[js][nt];
        p0 += fmaxf(v[0], 0.f) * w3[nt];
        p1 += fmaxf(v[1], 0.f) * w3[nt];
        p2 += fmaxf(v[2], 0.f) * w3[nt];
        p3 += fmaxf(v[3], 0.f) * w3[nt];
      }
      #pragma unroll
      for (int m = 1; m <= 8; m <<= 1) {
        p0 += __shfl_xor(p0, m, 64);
        p1 += __shfl_xor(p1, m, 64);
        p2 += __shfl_xor(p2, m, 64);
        p3 += __shfl_xor(p3, m, 64);
      }
      if (r == 0) {
        int jb2 = j0 + js * 16 + 4 * g;
        int j;
        float logit;
        j = jb2 + 0;
        if (j > i) {
          logit = p0 * INV_SH + be3v;
          out[i * (NN - 1) - (i * (i - 1)) / 2 + (j - i - 1)] =
              1.0f / (1.0f + expf(-logit));
        }
        j = jb2 + 1;
        if (j > i) {
          logit = p1 * INV_SH + be3v;
          out[i * (NN - 1) - (i * (i - 1)) / 2 + (j - i - 1)] =
              1.0f / (1.0f + expf(-logit));
        }
        j = jb2 + 2;
        if (j > i) {
          logit = p2 * INV_SH + be3v;
          out[i * (NN - 1) - (i * (i - 1)) / 2 + (j - i - 1)] =
              1.0f / (1.0f + expf(-logit));
        }
        j = jb2 + 3;
        if (j > i) {
          logit = p3 * INV_SH + be3v;
          out[i * (NN - 1) - (i * (i - 1)) / 2 + (j - i - 1)] =
              1.0f / (1.0f + expf(-logit));
        }
      }
    }
  }
}

extern "C" void kernel_launch(void* const* d_in, const int* in_sizes, int n_in,
                              void* d_out, int out_size, void* d_ws, size_t ws_size,
                              hipStream_t stream) {
  (void)in_sizes; (void)n_in; (void)out_size; (void)ws_size;
  const float* nf  = (const float*)d_in[0];
  const float* adj = (const float*)d_in[1];
  const float* W0  = (const float*)d_in[2];
  const float* b0  = (const float*)d_in[3];
  const float* W1  = (const float*)d_in[4];
  const float* b1  = (const float*)d_in[5];
  const float* W2  = (const float*)d_in[6];
  const float* b2  = (const float*)d_in[7];
  const float* We1 = (const float*)d_in[8];
  const float* be1 = (const float*)d_in[9];
  const float* We2 = (const float*)d_in[10];
  const float* be2 = (const float*)d_in[11];
  const float* We3 = (const float*)d_in[12];
  const float* be3 = (const float*)d_in[13];
  float* out = (float*)d_out;

  // Workspace layout (max 3584 KB):
  //  [0,512K):    x0, later overwritten by x2 (x0 dead after layer 1)
  //  [512K,1024K): x1
  //  [1024K,1040K): Whg ; [1040K,1056K): Wlg
  //  [1536K,2560K): Ab ; [2560K,3584K): Bb
  char* ws = (char*)d_ws;
  float* x0 = (float*)(ws);
  float* x1 = (float*)(ws + (512 << 10));
  float* x2 = (float*)(ws);                        // reuse x0 slot
  _Float16* Whg = (_Float16*)(ws + (1024 << 10));  // 16 KB
  _Float16* Wlg = (_Float16*)(ws + (1040 << 10));  // 16 KB
  float* Ab = (float*)(ws + (1536 << 10));         // 1 MB (pre-scaled)
  float* Bb = (float*)(ws + (2560 << 10));         // 1 MB (pre-scaled)

  wsplit_kernel<<<32, 256, 0, stream>>>(We2, Whg, Wlg);
  gcn0_kernel<<<NN / 4, 256, 0, stream>>>(adj, nf, W0, b0, x0);
  gcnL_kernel<<<NN / 4, 256, 0, stream>>>(adj, x0, W1, b1, x1,
                                          nullptr, nullptr, nullptr, nullptr);
  gcnL_kernel<<<NN / 4, 256, 0, stream>>>(adj, x1, W2, b2, x2,
                                          We1, be1, Ab, Bb);
  pair_kernel<<<dim3(NN / 32, NN / 32), 512, 0, stream>>>(Ab, Bb, Whg, Wlg,
                                                          be2, We3, be3, out);
}

// Round 17
// 250.286 us; speedup vs baseline: 2.0020x; 1.0300x over previous
//
#include <hip/hip_runtime.h>
#include <math.h>

#define NN 2048
#define HH 64

typedef _Float16 half8 __attribute__((ext_vector_type(8)));
typedef _Float16 half2_t __attribute__((ext_vector_type(2)));
typedef float f32x4 __attribute__((ext_vector_type(4)));

#define SH (1.0f / 256.0f)
#define INV_SH 256.0f
#define BPAD 132  // f32 row stride: 2-way bank phases (free)

#if defined(__has_builtin)
#if __has_builtin(__builtin_amdgcn_cvt_pkrtz)
#define PKRTZ(a, b) ((half2_t)__builtin_amdgcn_cvt_pkrtz((a), (b)))
#endif
#endif
#ifndef PKRTZ
#define PKRTZ(a, b) ((half2_t){(_Float16)(a), (_Float16)(b)})
#endif

union H8u { half2_t h2[4]; half8 h8; };

// ---------- layer 0: x0 = relu((adj @ nf) @ W0 + b0), nf is (N,4) ----------
// v2: f32 accumulation (validated by gcnL round-16: sum error ~1e-5 absolute,
// logit budget ~0.08). f64 kept only for the 4-term W0 dot.
__global__ __launch_bounds__(256) void gcn0_kernel(const float* __restrict__ adj,
                                                   const float* __restrict__ nf,
                                                   const float* __restrict__ W0,
                                                   const float* __restrict__ b0,
                                                   float* __restrict__ xout) {
  int w = threadIdx.x >> 6;
  int l = threadIdx.x & 63;
  int i = blockIdx.x * 4 + w;
  const float* arow = adj + (size_t)i * NN;
  float s0 = 0.f, s1 = 0.f, s2 = 0.f, s3 = 0.f;
  for (int k = l; k < NN; k += 64) {
    float a = arow[k];
    float4 v = *(const float4*)(nf + (size_t)k * 4);
    s0 = fmaf(a, v.x, s0);
    s1 = fmaf(a, v.y, s1);
    s2 = fmaf(a, v.z, s2);
    s3 = fmaf(a, v.w, s3);
  }
  #pragma unroll
  for (int m = 32; m >= 1; m >>= 1) {
    s0 += __shfl_xor(s0, m, 64);
    s1 += __shfl_xor(s1, m, 64);
    s2 += __shfl_xor(s2, m, 64);
    s3 += __shfl_xor(s3, m, 64);
  }
  double y = (double)b0[l];
  y += (double)s0 * (double)W0[0 * HH + l];
  y += (double)s1 * (double)W0[1 * HH + l];
  y += (double)s2 * (double)W0[2 * HH + l];
  y += (double)s3 * (double)W0[3 * HH + l];
  float r = (float)y;
  xout[(size_t)i * HH + l] = r > 0.f ? r : 0.f;
}

// ---------- layers 1,2: xout = relu((adj @ xin) @ W + b); layer2 fuses A/B ----------
// v3: 512 threads (8 waves). Wave w handles K-slice [16w,16w+16) for all 4
// rows -> per-thread staging halves, barrier count amortized over 2x waves,
// LDS 44 KB -> 3 blocks/CU x 8 waves. Epilogue on waves 0-3.
#define KT 128
__global__ __launch_bounds__(512) void gcnL_kernel(const float* __restrict__ adj,
                                                   const float* __restrict__ xin,
                                                   const float* __restrict__ W,
                                                   const float* __restrict__ b,
                                                   float* __restrict__ xout,
                                                   const float* __restrict__ We1,
                                                   const float* __restrict__ be1,
                                                   float* __restrict__ Aout,
                                                   float* __restrict__ Bout) {
  __shared__ float xs[KT][HH];        // 32 KB [kk][l]
  __shared__ float adjs[4][KT];       // 2 KB  [row][kk]
  __shared__ float sredp[8][4][HH];   // 8 KB  [wave][row][l] K-slice partials
  __shared__ float sredt[4][HH];      // 1 KB  full row sums
  __shared__ float xr2[4][HH];        // 1 KB
  int tid = threadIdx.x;
  int w = tid >> 6, l = tid & 63;
  int i0 = blockIdx.x * 4;
  float acc0 = 0.f, acc1 = 0.f, acc2 = 0.f, acc3 = 0.f;  // rows 0..3, K-slice [16w,16w+16)
  for (int k0 = 0; k0 < NN; k0 += KT) {
    __syncthreads();
    const float4* xsrc = (const float4*)(xin + (size_t)k0 * HH);
    float4* xdst = (float4*)&xs[0][0];
    for (int idx = tid; idx < KT * HH / 4; idx += 512) xdst[idx] = xsrc[idx];
    for (int idx = tid; idx < 4 * KT / 4; idx += 512) {
      int r = idx >> 5, c4 = idx & 31;
      *(float4*)&adjs[r][c4 * 4] =
          *(const float4*)(adj + (size_t)(i0 + r) * NN + k0 + c4 * 4);
    }
    __syncthreads();
    int kbase = w * 16;
    #pragma unroll
    for (int kq = 0; kq < 4; ++kq) {
      int kk = kbase + kq * 4;
      float4 a0 = *(const float4*)&adjs[0][kk];  // wave-uniform broadcast
      float4 a1 = *(const float4*)&adjs[1][kk];
      float4 a2 = *(const float4*)&adjs[2][kk];
      float4 a3 = *(const float4*)&adjs[3][kk];
      float xv0 = xs[kk + 0][l];
      float xv1 = xs[kk + 1][l];
      float xv2 = xs[kk + 2][l];
      float xv3 = xs[kk + 3][l];
      acc0 = fmaf(a0.w, xv3, fmaf(a0.z, xv2, fmaf(a0.y, xv1, fmaf(a0.x, xv0, acc0))));
      acc1 = fmaf(a1.w, xv3, fmaf(a1.z, xv2, fmaf(a1.y, xv1, fmaf(a1.x, xv0, acc1))));
      acc2 = fmaf(a2.w, xv3, fmaf(a2.z, xv2, fmaf(a2.y, xv1, fmaf(a2.x, xv0, acc2))));
      acc3 = fmaf(a3.w, xv3, fmaf(a3.z, xv2, fmaf(a3.y, xv1, fmaf(a3.x, xv0, acc3))));
    }
  }
  sredp[w][0][l] = acc0;
  sredp[w][1][l] = acc1;
  sredp[w][2][l] = acc2;
  sredp[w][3][l] = acc3;
  __syncthreads();
  if (w < 4) {
    float s = 0.f;
    #pragma unroll
    for (int sw = 0; sw < 8; ++sw) s += sredp[sw][w][l];
    sredt[w][l] = s;
  }
  __syncthreads();
  if (w < 4) {
    double y = (double)b[l];
    #pragma unroll 8
    for (int d = 0; d < HH; ++d) y += (double)sredt[w][d] * (double)W[d * HH + l];
    float r = (float)y;
    float rres = r > 0.f ? r : 0.f;
    xout[(size_t)(i0 + w) * HH + l] = rres;
    if (Aout != nullptr) xr2[w][l] = rres;
  }
  if (Aout != nullptr) {
    __syncthreads();
    {
      int idx = tid;                   // 0..511 covers 4 rows x 128 cols
      int rr = idx >> 7, c = idx & 127;
      const float* xr = xr2[rr];
      float accA = be1[c], accB = 0.f;
      #pragma unroll 8
      for (int d = 0; d < HH; ++d) {
        float xv = xr[d];
        accA = fmaf(xv, We1[d * 128 + c], accA);
        accB = fmaf(xv, We1[(HH + d) * 128 + c], accB);
      }
      Aout[(size_t)(i0 + rr) * 128 + c] = accA * SH;
      Bout[(size_t)(i0 + rr) * 128 + c] = accB * SH;
    }
  }
}

// ---------- one-shot We2 split: Wh/Wl f16 [c2][k] row-major ----------
__global__ __launch_bounds__(256) void wsplit_kernel(const float* __restrict__ We2,
                                                     _Float16* __restrict__ Whg,
                                                     _Float16* __restrict__ Wlg) {
  int idx = blockIdx.x * 256 + threadIdx.x;   // 0..8191
  int k = idx >> 6, c2 = idx & 63;
  float wv = We2[idx];
  _Float16 hi = (_Float16)wv;
  float lo = wv - (float)hi;
  Whg[c2 * 128 + k] = hi;
  Wlg[c2 * 128 + k] = (_Float16)lo;
}

// ---------- pair MLP via MFMA (split-f16), 32i x 32j tile, 8 waves ----------
// v10 (rounds 15/16, unchanged): js=2, acc=32 regs, VGPR 64; 512-thread
// blocks amortize the 32 KB W-tile over 8 waves. 170 us, occ 25%.
__global__ __launch_bounds__(512, 4) void pair_kernel(const float* __restrict__ A,
                                                      const float* __restrict__ B,
                                                      const _Float16* __restrict__ Whg,
                                                      const _Float16* __restrict__ Wlg,
                                                      const float* __restrict__ be2,
                                                      const float* __restrict__ We3,
                                                      const float* __restrict__ be3,
                                                      float* __restrict__ out) {
  int j0 = blockIdx.x * 32;
  int i0 = blockIdx.y * 32;
  if (i0 >= j0 + 31) return;         // no pair (i<j) in tile
  __shared__ __align__(16) _Float16 Wst8[2048 * 8];  // 32 KB, [Wh|Wl] swizzled
  __shared__ __align__(16) float Bs[32][BPAD];       // 16.9 KB
  __shared__ float be2s[64];
  __shared__ float We3s[64];
  int tid = threadIdx.x;
  int w = tid >> 6, l = tid & 63;   // 8 waves
  int r = l & 15, g = l >> 4;

  {
    half8* Wst = (half8*)Wst8;
    #pragma unroll
    for (int t = 0; t < 4; ++t) {
      int idx = tid + t * 512;       // 0..2047
      int arr = idx >> 10;           // 0 = Wh, 1 = Wl
      int c = idx & 1023;
      int row = c >> 4, ch = c & 15;
      const half8* src = arr ? (const half8*)Wlg : (const half8*)Whg;
      Wst[arr * 1024 + row * 16 + (ch ^ (row & 15))] = src[c];
    }
  }
  #pragma unroll
  for (int t = 0; t < 2; ++t) {
    int idx = tid + t * 512;         // 0..1023
    int rr = idx >> 5, c4 = idx & 31;
    *(float4*)&Bs[rr][c4 * 4] = *(const float4*)(B + (size_t)(j0 + rr) * 128 + c4 * 4);
  }
  if (tid < 64) { be2s[tid] = be2[tid]; We3s[tid] = We3[tid]; }
  __syncthreads();

  const half8* Wst = (const half8*)Wst8;
  float be3v = be3[0];
  float w3[4], sb[4];
  #pragma unroll
  for (int nt = 0; nt < 4; ++nt) {
    w3[nt] = We3s[nt * 16 + r];
    sb[nt] = SH * be2s[nt * 16 + r];
  }

  #pragma unroll 1
  for (int p = 0; p < 4; ++p) {
    int ir = w * 4 + p;              // wave-uniform, 0..31
    int i = i0 + ir;
    if (i >= j0 + 31) continue;
    const float* Arow = A + (size_t)i * 128;
    f32x4 acc[2][4];
    #pragma unroll
    for (int js = 0; js < 2; ++js) {
      #pragma unroll
      for (int nt = 0; nt < 4; ++nt) {
        acc[js][nt][0] = sb[nt]; acc[js][nt][1] = sb[nt];
        acc[js][nt][2] = sb[nt]; acc[js][nt][3] = sb[nt];
      }
    }
    #pragma unroll
    for (int ks = 0; ks < 4; ++ks) {
      int kb = ks * 32 + 8 * g;
      half8 wh[4], wl[4];
      #pragma unroll
      for (int nt = 0; nt < 4; ++nt) {
        int a = (nt * 16 + r) * 16 + ((ks * 4 + g) ^ r);
        wh[nt] = Wst[a];
        wl[nt] = Wst[1024 + a];
      }
      float4 a0 = *(const float4*)(Arow + kb);      // L1/L2-resident, uniform row
      float4 a1 = *(const float4*)(Arow + kb + 4);
      #pragma unroll
      for (int js = 0; js < 2; ++js) {
        float4 b0 = *(const float4*)&Bs[js * 16 + r][kb];
        float4 b1 = *(const float4*)&Bs[js * 16 + r][kb + 4];
        float s0 = fmaxf(a0.x + b0.x, 0.f);
        float s1 = fmaxf(a0.y + b0.y, 0.f);
        float s2 = fmaxf(a0.z + b0.z, 0.f);
        float s3 = fmaxf(a0.w + b0.w, 0.f);
        float s4 = fmaxf(a1.x + b1.x, 0.f);
        float s5 = fmaxf(a1.y + b1.y, 0.f);
        float s6 = fmaxf(a1.z + b1.z, 0.f);
        float s7 = fmaxf(a1.w + b1.w, 0.f);
        H8u hh, hl;
        hh.h2[0] = PKRTZ(s0, s1);
        hh.h2[1] = PKRTZ(s2, s3);
        hh.h2[2] = PKRTZ(s4, s5);
        hh.h2[3] = PKRTZ(s6, s7);
        hl.h2[0] = PKRTZ(s0 - (float)hh.h2[0][0], s1 - (float)hh.h2[0][1]);
        hl.h2[1] = PKRTZ(s2 - (float)hh.h2[1][0], s3 - (float)hh.h2[1][1]);
        hl.h2[2] = PKRTZ(s4 - (float)hh.h2[2][0], s5 - (float)hh.h2[2][1]);
        hl.h2[3] = PKRTZ(s6 - (float)hh.h2[3][0], s7 - (float)hh.h2[3][1]);
        #pragma unroll
        for (int nt = 0; nt < 4; ++nt) {
          acc[js][nt] = __builtin_amdgcn_mfma_f32_16x16x32_f16(hh.h8, wh[nt], acc[js][nt], 0, 0, 0);
          acc[js][nt] = __builtin_amdgcn_mfma_f32_16x16x32_f16(hh.h8, wl[nt], acc[js][nt], 0, 0, 0);
          acc[js][nt] = __builtin_amdgcn_mfma_f32_16x16x32_f16(hl.h8, wh[nt], acc[js][nt], 0, 0, 0);
        }
      }
    }
    // epilogue: h2 = relu(acc)/SH; logit = sum h2*We3 + be3; direct store
    #pragma unroll
    for (int js = 0; js < 2; ++js) {
      float p0 = 0.f, p1 = 0.f, p2 = 0.f, p3 = 0.f;
      #pragma unroll
      for (int nt = 0; nt < 4; ++nt) {
        f32x4 v = acc[js][nt];
        p0 += fmaxf(v[0], 0.f) * w3[nt];
        p1 += fmaxf(v[1], 0.f) * w3[nt];
        p2 += fmaxf(v[2], 0.f) * w3[nt];
        p3 += fmaxf(v[3], 0.f) * w3[nt];
      }
      #pragma unroll
      for (int m = 1; m <= 8; m <<= 1) {
        p0 += __shfl_xor(p0, m, 64);
        p1 += __shfl_xor(p1, m, 64);
        p2 += __shfl_xor(p2, m, 64);
        p3 += __shfl_xor(p3, m, 64);
      }
      if (r == 0) {
        int jb2 = j0 + js * 16 + 4 * g;
        int j;
        float logit;
        j = jb2 + 0;
        if (j > i) {
          logit = p0 * INV_SH + be3v;
          out[i * (NN - 1) - (i * (i - 1)) / 2 + (j - i - 1)] =
              1.0f / (1.0f + expf(-logit));
        }
        j = jb2 + 1;
        if (j > i) {
          logit = p1 * INV_SH + be3v;
          out[i * (NN - 1) - (i * (i - 1)) / 2 + (j - i - 1)] =
              1.0f / (1.0f + expf(-logit));
        }
        j = jb2 + 2;
        if (j > i) {
          logit = p2 * INV_SH + be3v;
          out[i * (NN - 1) - (i * (i - 1)) / 2 + (j - i - 1)] =
              1.0f / (1.0f + expf(-logit));
        }
        j = jb2 + 3;
        if (j > i) {
          logit = p3 * INV_SH + be3v;
          out[i * (NN - 1) - (i * (i - 1)) / 2 + (j - i - 1)] =
              1.0f / (1.0f + expf(-logit));
        }
      }
    }
  }
}

extern "C" void kernel_launch(void* const* d_in, const int* in_sizes, int n_in,
                              void* d_out, int out_size, void* d_ws, size_t ws_size,
                              hipStream_t stream) {
  (void)in_sizes; (void)n_in; (void)out_size; (void)ws_size;
  const float* nf  = (const float*)d_in[0];
  const float* adj = (const float*)d_in[1];
  const float* W0  = (const float*)d_in[2];
  const float* b0  = (const float*)d_in[3];
  const float* W1  = (const float*)d_in[4];
  const float* b1  = (const float*)d_in[5];
  const float* W2  = (const float*)d_in[6];
  const float* b2  = (const float*)d_in[7];
  const float* We1 = (const float*)d_in[8];
  const float* be1 = (const float*)d_in[9];
  const float* We2 = (const float*)d_in[10];
  const float* be2 = (const float*)d_in[11];
  const float* We3 = (const float*)d_in[12];
  const float* be3 = (const float*)d_in[13];
  float* out = (float*)d_out;

  // Workspace layout (max 3584 KB):
  //  [0,512K):    x0, later overwritten by x2 (x0 dead after layer 1)
  //  [512K,1024K): x1
  //  [1024K,1040K): Whg ; [1040K,1056K): Wlg
  //  [1536K,2560K): Ab ; [2560K,3584K): Bb
  char* ws = (char*)d_ws;
  float* x0 = (float*)(ws);
  float* x1 = (float*)(ws + (512 << 10));
  float* x2 = (float*)(ws);                        // reuse x0 slot
  _Float16* Whg = (_Float16*)(ws + (1024 << 10));  // 16 KB
  _Float16* Wlg = (_Float16*)(ws + (1040 << 10));  // 16 KB
  float* Ab = (float*)(ws + (1536 << 10));         // 1 MB (pre-scaled)
  float* Bb = (float*)(ws + (2560 << 10));         // 1 MB (pre-scaled)

  wsplit_kernel<<<32, 256, 0, stream>>>(We2, Whg, Wlg);
  gcn0_kernel<<<NN / 4, 256, 0, stream>>>(adj, nf, W0, b0, x0);
  gcnL_kernel<<<NN / 4, 512, 0, stream>>>(adj, x0, W1, b1, x1,
                                          nullptr, nullptr, nullptr, nullptr);
  gcnL_kernel<<<NN / 4, 512, 0, stream>>>(adj, x1, W2, b2, x2,
                                          We1, be1, Ab, Bb);
  pair_kernel<<<dim3(NN / 32, NN / 32), 512, 0, stream>>>(Ab, Bb, Whg, Wlg,
                                                          be2, We3, be3, out);
}